// Round 3
// baseline (19586.259 us; speedup 1.0000x reference)
//
#include <hip/hip_runtime.h>
#include <cstdint>
#include <cstddef>

// Autoregressive LSTM cell with softmax feedback. B=256, T=512, D=512, N=64.
// Persistent (non-cooperative) kernel: 128 blocks x 256 threads.
//   group g = rows [g*64, g*64+64); block covers d-tile dt (16 d x 4 gates = 64 gate-cols).
// Per step: y-phase (softmax(h_{t-1}) via MFMA, redundant per block) -> syncthreads ->
//           gates GEMM K=1088 (x | h | y) -> LSTM elementwise -> h write (double-buffered)
//           -> ONE flag-based (no-RMW) global barrier per group per step.
// Numerics: fp16 hi/lo split operands (exact to ~2^-22), 3-pass MFMA, fp32 accum/state.
//
// R3 change vs R2 (19.4ms, MfmaUtil 5.3%, barrier-bound): the R2 barrier used 32
// agent-scope atomicAdds per group on counters that shared ONE cacheline across all
// 4 groups -> ~128 serialized cross-XCD RMWs/step (~34us/step). Replaced with
// padded-slot store barrier + lane-parallel leader poll + epoch broadcast.

typedef _Float16 f16x8 __attribute__((ext_vector_type(8)));
typedef float f32x4 __attribute__((ext_vector_type(4)));

#define MFMA16(a, b, c_) __builtin_amdgcn_mfma_f32_16x16x32_f16((a), (b), (c_), 0, 0, 0)

// bar layout (ints, 64-int = 256B stride): arrival slot (g*32+bq) at (g*32+bq)*64,
// epoch[g] at (128+g)*64, abort at 132*64. Total 8512 ints.
#define BAR_INTS 8512

__device__ __forceinline__ void cvt8(const float4 a, const float4 b, f16x8& hi, f16x8& lo) {
  float v[8] = {a.x, a.y, a.z, a.w, b.x, b.y, b.z, b.w};
#pragma unroll
  for (int j = 0; j < 8; ++j) {
    _Float16 h = (_Float16)v[j];
    hi[j] = h;
    lo[j] = (_Float16)(v[j] - (float)h);
  }
}

// ---------------------------------------------------------------------------
// prep: fragment-ordered fp16 hi|lo buffers. Slot map sigma(h,j)=4h+(j&3)+16*(j>>2)
// (same bijection used for A and B fragments -> MFMA result independent of HW k-order).
// ---------------------------------------------------------------------------
template <bool XPRE>
__global__ void prep_kernel(const float* __restrict__ x, const float* __restrict__ init_h,
                            const float* __restrict__ W_ih, const float* __restrict__ b_ih,
                            const float* __restrict__ W_hh, const float* __restrict__ b_hh,
                            const float* __restrict__ W_lin,
                            _Float16* __restrict__ xs, _Float16* __restrict__ wf,
                            _Float16* __restrict__ wl, _Float16* __restrict__ hs,
                            float* __restrict__ bias, int* __restrict__ bar) {
  const int NX = XPRE ? 256 * 512 * 16 * 4 : 0;  // (row,t,ki,h) -> 8 elements
  const int NWF = 128 * 34 * 64;                 // (ct,ki,l)
  const int NWL = 4 * 16 * 64;
  const int NH = 256 * 16 * 4;
  int tid = blockIdx.x * 256 + threadIdx.x;

  if (XPRE && tid < NX) {
    int h = tid & 3, ki = (tid >> 2) & 15, t = (tid >> 6) & 511, row = tid >> 15;
    const float* s = x + (((size_t)row * 512 + t) * 512 + ki * 32 + 4 * h);
    float4 a = *(const float4*)s, b = *(const float4*)(s + 16);
    f16x8 hi, lo;
    cvt8(a, b, hi, lo);
    _Float16* d = xs + ((((size_t)row * 512 + t) * 16 + ki) * 64 + h * 16);
    *(f16x8*)d = hi;
    *(f16x8*)(d + 8) = lo;
    return;
  }
  int u = tid - NX;
  if (u >= 0 && u < NWF) {
    int l = u & 63, u2 = u >> 6;
    int ki = u2 % 34, ct = u2 / 34;
    int col = ct * 16 + (l & 15), h = l >> 4;
    int k = ki * 32 + 4 * h;
    float4 a, b;
    if (k < 512) {
      const float* p = W_ih + (size_t)col * 576;
      a = *(const float4*)(p + k);
      b = *(const float4*)(p + k + 16);
    } else if (k < 1024) {
      const float* p = W_hh + (size_t)col * 512;
      a = *(const float4*)(p + k - 512);
      b = *(const float4*)(p + k - 512 + 16);
    } else {
      const float* p = W_ih + (size_t)col * 576 + 512;
      a = *(const float4*)(p + k - 1024);
      b = *(const float4*)(p + k - 1024 + 16);
    }
    f16x8 hi, lo;
    cvt8(a, b, hi, lo);
    _Float16* d = wf + (((size_t)ct * 34 + ki) * 64 + l) * 16;
    *(f16x8*)d = hi;
    *(f16x8*)(d + 8) = lo;
    return;
  }
  u -= NWF;
  if (u >= 0 && u < NWL) {
    int l = u & 63, u2 = u >> 6;
    int ki = u2 & 15, ct = u2 >> 4;
    int col = ct * 16 + (l & 15), h = l >> 4;
    int k = ki * 32 + 4 * h;
    const float* p = W_lin + (size_t)col * 512;
    float4 a = *(const float4*)(p + k), b = *(const float4*)(p + k + 16);
    f16x8 hi, lo;
    cvt8(a, b, hi, lo);
    _Float16* d = wl + (((size_t)ct * 16 + ki) * 64 + l) * 16;
    *(f16x8*)d = hi;
    *(f16x8*)(d + 8) = lo;
    return;
  }
  u -= NWL;
  if (u >= 0 && u < NH) {
    int h = u & 3, ki = (u >> 2) & 15, row = u >> 6;
    const float* s = init_h + ((size_t)row * 512 + ki * 32 + 4 * h);
    float4 a = *(const float4*)s, b = *(const float4*)(s + 16);
    f16x8 hi, lo;
    cvt8(a, b, hi, lo);
    _Float16* d = hs + (((size_t)row * 16 + ki) * 64 + h * 16);  // buffer 0
    *(f16x8*)d = hi;
    *(f16x8*)(d + 8) = lo;
    return;
  }
  u -= NH;
  if (u >= 0 && u < 2048) {
    bias[u] = b_ih[u] + b_hh[u];
    return;
  }
  u -= 2048;
  if (u >= 0 && u < BAR_INTS) bar[u] = 0;
}

// Flag-based per-group barrier, no RMW, 256B-padded slots, timeout-guarded.
// Non-leader (bq<31): RELEASE-store step1 to own slot; ACQUIRE-spin on epoch[g].
// Leader (bq==31): lanes 0..30 ACQUIRE-spin on slot[lane]; then RELEASE-store epoch[g]=step1.
__device__ __forceinline__ void gbar(int* __restrict__ bar, int g, int bq, int step1,
                                     int* s_ab) {
  __syncthreads();  // drains this block's stores (compiler emits vmcnt(0) before s_barrier)
  int* abortf = bar + 132 * 64;
  if (bq == 31) {
    if (threadIdx.x < 32) {
      int a = 0;
      if (threadIdx.x < 31) {
        int* s = bar + (g * 32 + (int)threadIdx.x) * 64;
        int it = 0;
        while (__hip_atomic_load(s, __ATOMIC_ACQUIRE, __HIP_MEMORY_SCOPE_AGENT) < step1) {
          __builtin_amdgcn_s_sleep(0);
          if (++it > 2000000) {  // never hang: visible failure instead
            a = 1;
            break;
          }
          if ((it & 1023) == 0 &&
              __hip_atomic_load(abortf, __ATOMIC_RELAXED, __HIP_MEMORY_SCOPE_AGENT) != 0) {
            a = 1;
            break;
          }
        }
      }
      a = __any(a) ? 1 : 0;
      if (threadIdx.x == 0) {
        if (a)
          __hip_atomic_store(abortf, 1, __ATOMIC_RELAXED, __HIP_MEMORY_SCOPE_AGENT);
        else
          __hip_atomic_store(bar + (128 + g) * 64, step1, __ATOMIC_RELEASE,
                             __HIP_MEMORY_SCOPE_AGENT);
        *s_ab = a;
      }
    }
  } else {
    if (threadIdx.x == 0) {
      int a = 0;
      __hip_atomic_store(bar + (g * 32 + bq) * 64, step1, __ATOMIC_RELEASE,
                         __HIP_MEMORY_SCOPE_AGENT);
      int* ep = bar + (128 + g) * 64;
      int it = 0;
      while (__hip_atomic_load(ep, __ATOMIC_ACQUIRE, __HIP_MEMORY_SCOPE_AGENT) < step1) {
        __builtin_amdgcn_s_sleep(1);
        if (++it > 1000000) {
          a = 1;
          __hip_atomic_store(abortf, 1, __ATOMIC_RELAXED, __HIP_MEMORY_SCOPE_AGENT);
          break;
        }
        if ((it & 255) == 0 &&
            __hip_atomic_load(abortf, __ATOMIC_RELAXED, __HIP_MEMORY_SCOPE_AGENT) != 0) {
          a = 1;
          break;
        }
      }
      *s_ab = a;
    }
  }
  __syncthreads();
}

#define GATES_MFMA(KI)                                                         \
  {                                                                            \
    const _Float16* B0 = wf0 + (size_t)(KI)*1024;                              \
    const _Float16* B1 = wf1 + (size_t)(KI)*1024;                              \
    const _Float16* B2 = wf2 + (size_t)(KI)*1024;                              \
    const _Float16* B3 = wf3 + (size_t)(KI)*1024;                              \
    f16x8 b0h = *(const f16x8*)B0, b1h = *(const f16x8*)B1;                    \
    f16x8 b2h = *(const f16x8*)B2, b3h = *(const f16x8*)B3;                    \
    a0 = MFMA16(ah, b0h, a0);                                                  \
    a1 = MFMA16(ah, b1h, a1);                                                  \
    a2 = MFMA16(ah, b2h, a2);                                                  \
    a3 = MFMA16(ah, b3h, a3);                                                  \
    a0 = MFMA16(al, b0h, a0);                                                  \
    a1 = MFMA16(al, b1h, a1);                                                  \
    a2 = MFMA16(al, b2h, a2);                                                  \
    a3 = MFMA16(al, b3h, a3);                                                  \
    f16x8 b0l = *(const f16x8*)(B0 + 8), b1l = *(const f16x8*)(B1 + 8);        \
    f16x8 b2l = *(const f16x8*)(B2 + 8), b3l = *(const f16x8*)(B3 + 8);        \
    a0 = MFMA16(ah, b0l, a0);                                                  \
    a1 = MFMA16(ah, b1l, a1);                                                  \
    a2 = MFMA16(ah, b2l, a2);                                                  \
    a3 = MFMA16(ah, b3l, a3);                                                  \
  }

template <bool XPRE>
__global__ void __launch_bounds__(256, 1) recur_kernel(
    const float* __restrict__ x, const float* __restrict__ b_lin,
    const _Float16* __restrict__ xs, const _Float16* __restrict__ wf,
    const _Float16* __restrict__ wl, _Float16* __restrict__ hs, const float* __restrict__ bias,
    float* __restrict__ out, int* __restrict__ bar) {
  const int p = blockIdx.x;
  const int g = p >> 5;                               // XCD swizzle: XCD(p)=p%8 = dt>>2
  const int dt = ((p & 7) << 2) + ((p >> 3) & 3);     // -> blocks sharing wf slices co-locate
  const int bq = p & 31;                              // index within group (leader: 31)
  const int tid = threadIdx.x;
  const int l = tid & 63, w = tid >> 6;
  const int l15 = l & 15, q = l >> 4;
  const int r0 = g * 64, R = w * 16;
  const int growA = r0 + R + l15;

  __shared__ _Float16 ys[64 * 128];  // 16KB: y feedback slots, XOR-swizzled
  __shared__ int s_ab;

  const size_t HSTRIDE = (size_t)256 * 16 * 64;
  const int d0 = dt * 16;
  const float bg0 = bias[0 * 512 + d0 + l15];
  const float bg1 = bias[1 * 512 + d0 + l15];
  const float bg2 = bias[2 * 512 + d0 + l15];
  const float bg3 = bias[3 * 512 + d0 + l15];
  const float bl0 = b_lin[0 + l15], bl1 = b_lin[16 + l15];
  const float bl2 = b_lin[32 + l15], bl3 = b_lin[48 + l15];

  const _Float16* wf0 = wf + (size_t)(0 * 32 + dt) * 34816 + (size_t)l * 16;
  const _Float16* wf1 = wf + (size_t)(1 * 32 + dt) * 34816 + (size_t)l * 16;
  const _Float16* wf2 = wf + (size_t)(2 * 32 + dt) * 34816 + (size_t)l * 16;
  const _Float16* wf3 = wf + (size_t)(3 * 32 + dt) * 34816 + (size_t)l * 16;

  const _Float16* hsA = hs + (size_t)growA * 1024 + q * 16;   // + buf*HSTRIDE + ki*64
  const _Float16* xsA = xs + (size_t)growA * 524288 + q * 16; // + t*1024 + ki*64 (XPRE)
  const float* xfA = x + (size_t)growA * 262144 + 4 * q;      // + t*512 + ki*32 (fallback)

  const int kiW = dt >> 1;
  const int jW = (l15 & 3) + 4 * (dt & 1);
  const int hW = l15 >> 2;
  _Float16* hwbase = hs + (((size_t)(r0 + R + 4 * q) * 16 + kiW) * 64 + hW * 16 + jW);

  const f32x4 Z = {0.f, 0.f, 0.f, 0.f};
  f32x4 cst = Z;  // cell state in registers for all 512 steps

  // y-phase: logits = h @ W_lin^T + b_lin (MFMA, hi/lo), softmax, LDS slots (+ out)
  auto yphase = [&](int tcur, const _Float16* hA, bool writeLDS) {
    f32x4 y0 = Z, y1 = Z, y2 = Z, y3 = Z;
#pragma unroll 2
    for (int ki = 0; ki < 16; ++ki) {
      const _Float16* Ap = hA + (size_t)ki * 64;
      f16x8 ah = *(const f16x8*)Ap, al = *(const f16x8*)(Ap + 8);
      const _Float16* B0 = wl + (size_t)ki * 1024 + (size_t)l * 16;
      const _Float16* B1 = B0 + 16384;
      const _Float16* B2 = B0 + 32768;
      const _Float16* B3 = B0 + 49152;
      f16x8 b0h = *(const f16x8*)B0, b1h = *(const f16x8*)B1;
      f16x8 b2h = *(const f16x8*)B2, b3h = *(const f16x8*)B3;
      y0 = MFMA16(ah, b0h, y0);
      y1 = MFMA16(ah, b1h, y1);
      y2 = MFMA16(ah, b2h, y2);
      y3 = MFMA16(ah, b3h, y3);
      y0 = MFMA16(al, b0h, y0);
      y1 = MFMA16(al, b1h, y1);
      y2 = MFMA16(al, b2h, y2);
      y3 = MFMA16(al, b3h, y3);
      f16x8 b0l = *(const f16x8*)(B0 + 8), b1l = *(const f16x8*)(B1 + 8);
      f16x8 b2l = *(const f16x8*)(B2 + 8), b3l = *(const f16x8*)(B3 + 8);
      y0 = MFMA16(ah, b0l, y0);
      y1 = MFMA16(ah, b1l, y1);
      y2 = MFMA16(ah, b2l, y2);
      y3 = MFMA16(ah, b3l, y3);
    }
#pragma unroll
    for (int r = 0; r < 4; ++r) {
      float v0 = y0[r] + bl0, v1 = y1[r] + bl1, v2 = y2[r] + bl2, v3 = y3[r] + bl3;
      float m = fmaxf(fmaxf(v0, v1), fmaxf(v2, v3));
      m = fmaxf(m, __shfl_xor(m, 1));
      m = fmaxf(m, __shfl_xor(m, 2));
      m = fmaxf(m, __shfl_xor(m, 4));
      m = fmaxf(m, __shfl_xor(m, 8));
      float e0 = __expf(v0 - m), e1 = __expf(v1 - m), e2 = __expf(v2 - m), e3 = __expf(v3 - m);
      float s = e0 + e1 + e2 + e3;
      s += __shfl_xor(s, 1);
      s += __shfl_xor(s, 2);
      s += __shfl_xor(s, 4);
      s += __shfl_xor(s, 8);
      float inv = 1.f / s;
      e0 *= inv;
      e1 *= inv;
      e2 *= inv;
      e3 *= inv;
      int rowL = R + 4 * q + r;
      if (writeLDS) {
        int swz = rowL & 7, base = rowL * 128, h2 = l15 >> 2;
        float ev[4] = {e0, e1, e2, e3};
#pragma unroll
        for (int ct = 0; ct < 4; ++ct) {
          _Float16 hh = (_Float16)ev[ct];
          _Float16 ll = (_Float16)(ev[ct] - (float)hh);
          int idx = base + ((((ct >> 1) * 4 + h2) ^ swz) * 16) + (l15 & 3) + 4 * (ct & 1);
          ys[idx] = hh;
          ys[idx + 8] = ll;
        }
      }
      if (dt == 0) {
        size_t ob = (((size_t)(r0 + rowL)) * 512 + tcur) * 64 + l15;
        out[ob] = e0;
        out[ob + 16] = e1;
        out[ob + 32] = e2;
        out[ob + 48] = e3;
      }
    }
  };

#pragma unroll 1
  for (int t = 0; t < 512; ++t) {
    const int rbuf = t & 1, wbuf = rbuf ^ 1;
    const _Float16* hA = hsA + (size_t)rbuf * HSTRIDE;
    if (t > 0) yphase(t - 1, hA, true);
    __syncthreads();  // ys visible to block

    f32x4 a0 = Z, a1 = Z, a2 = Z, a3 = Z;
    if (XPRE) {
      const _Float16* xA = xsA + (size_t)t * 1024;
#pragma unroll 2
      for (int ki = 0; ki < 16; ++ki) {
        const _Float16* Ap = xA + ki * 64;
        f16x8 ah = *(const f16x8*)Ap, al = *(const f16x8*)(Ap + 8);
        GATES_MFMA(ki);
      }
    } else {
      const float* xp = xfA + (size_t)t * 512;
#pragma unroll 2
      for (int ki = 0; ki < 16; ++ki) {
        float4 av = *(const float4*)(xp + ki * 32);
        float4 bv = *(const float4*)(xp + ki * 32 + 16);
        f16x8 ah, al;
        cvt8(av, bv, ah, al);
        GATES_MFMA(ki);
      }
    }
#pragma unroll 2
    for (int ki = 0; ki < 16; ++ki) {
      const _Float16* Ap = hA + ki * 64;
      f16x8 ah = *(const f16x8*)Ap, al = *(const f16x8*)(Ap + 8);
      GATES_MFMA(16 + ki);
    }
    if (t > 0) {
      const int rowL = R + l15, swz = rowL & 7;
#pragma unroll
      for (int kiy = 0; kiy < 2; ++kiy) {
        int idx = rowL * 128 + (((kiy * 4 + q) ^ swz) * 16);
        f16x8 ah = *(const f16x8*)(ys + idx), al = *(const f16x8*)(ys + idx + 8);
        GATES_MFMA(32 + kiy);
      }
    }

    _Float16* hw = hwbase + (size_t)wbuf * HSTRIDE;
#pragma unroll
    for (int r = 0; r < 4; ++r) {
      float zi = a0[r] + bg0, zf = a1[r] + bg1, zg = a2[r] + bg2, zo = a3[r] + bg3;
      float iv = 1.f / (1.f + __expf(-zi));
      float fv = 1.f / (1.f + __expf(-zf));
      float eg = __expf(2.f * zg);
      float gv = 1.f - 2.f / (eg + 1.f);  // tanh, inf-safe
      float ov = 1.f / (1.f + __expf(-zo));
      float cn = fv * cst[r] + iv * gv;
      cst[r] = cn;
      float ec = __expf(2.f * cn);
      float th = 1.f - 2.f / (ec + 1.f);
      float hv = ov * th;
      _Float16 hh = (_Float16)hv;
      _Float16 hl = (_Float16)(hv - (float)hh);
      hw[(size_t)r * 1024] = hh;
      hw[(size_t)r * 1024 + 8] = hl;
    }
    gbar(bar, g, bq, t + 1, &s_ab);
    if (s_ab) return;
  }
  if (dt == 0) yphase(511, hsA + (size_t)0 * HSTRIDE, false);  // h_511 is in buffer 0
}

extern "C" void kernel_launch(void* const* d_in, const int* in_sizes, int n_in, void* d_out,
                              int out_size, void* d_ws, size_t ws_size, hipStream_t stream) {
  const float* x = (const float*)d_in[0];
  const float* init_h = (const float*)d_in[1];
  const float* W_ih = (const float*)d_in[2];
  const float* b_ih = (const float*)d_in[3];
  const float* W_hh = (const float*)d_in[4];
  const float* b_hh = (const float*)d_in[5];
  const float* W_lin = (const float*)d_in[6];
  const float* b_lin = (const float*)d_in[7];
  float* out = (float*)d_out;
  (void)in_sizes;
  (void)n_in;
  (void)out_size;

  char* ws = (char*)d_ws;
  size_t off = 0;
  auto take = [&](size_t bytes) -> char* {
    char* r = ws + off;
    off = (off + bytes + 255) & ~(size_t)255;
    return r;
  };
  const size_t WF_E = (size_t)128 * 34 * 64 * 16;  // 4,456,448 f16
  const size_t WL_E = (size_t)4 * 16 * 64 * 16;    // 65,536
  const size_t HS_E = (size_t)2 * 256 * 16 * 64;   // 524,288 (double-buffered)
  const size_t XS_E = (size_t)256 * 512 * 16 * 64; // 134,217,728

  _Float16* wf = (_Float16*)take(WF_E * 2);
  _Float16* wl = (_Float16*)take(WL_E * 2);
  _Float16* hs = (_Float16*)take(HS_E * 2);
  float* bias = (float*)take(2048 * 4);
  int* bar = (int*)take(BAR_INTS * 4);
  if (ws_size < off) return;  // cannot run at all -> visible failure
  _Float16* xs = (_Float16*)(ws + off);
  const bool xpre = (ws_size >= off + XS_E * 2);

  if (xpre) {
    const int total = 8388608 + 278528 + 4096 + 16384 + 2048 + BAR_INTS;
    prep_kernel<true><<<(total + 255) / 256, 256, 0, stream>>>(x, init_h, W_ih, b_ih, W_hh, b_hh,
                                                               W_lin, xs, wf, wl, hs, bias, bar);
    recur_kernel<true><<<128, 256, 0, stream>>>(x, b_lin, xs, wf, wl, hs, bias, out, bar);
  } else {
    const int total = 278528 + 4096 + 16384 + 2048 + BAR_INTS;
    prep_kernel<false><<<(total + 255) / 256, 256, 0, stream>>>(x, init_h, W_ih, b_ih, W_hh, b_hh,
                                                                W_lin, xs, wf, wl, hs, bias, bar);
    recur_kernel<false><<<128, 256, 0, stream>>>(x, b_lin, xs, wf, wl, hs, bias, out, bar);
  }
}

// Round 4
// 18945.378 us; speedup vs baseline: 1.0338x; 1.0338x over previous
//
#include <hip/hip_runtime.h>
#include <cstdint>
#include <cstddef>

// Autoregressive LSTM cell with softmax feedback. B=256, T=512, D=512, N=64.
// R4 design: 256 uniform blocks x 512 threads (8 waves = 2 rowpairs x 2 colhalves x 2 K-halves),
// 1 block/CU (LDS 146KiB forces it -> guaranteed co-residency), 2 waves/SIMD.
// Block = [64 rows (group g) x 32 gate-cols ({i,f,g,o} x 8 d, d0=cb*8)].
// Weights (fused W_ih|W_hh|W_y, fp16 hi/lo, fragment-ordered) staged ONCE in LDS ->
// immune to the per-step L2 invalidation that killed R2/R3 (latency-bound at 19.4ms).
// y-logits: no GEMM. Block owns y-col cb; fp32 dots fused into the h-fragment stream
// (VALU pipe overlaps MFMA), shfl+LDS merge, 256B ylog write, flag barrier, in-register
// softmax -> y A-frags. Two flat-poll flag barriers/step (relaxed poll + one fence,
// monotone values, timeout->abort). hs double-buffered; c in registers; 3-pass fp16 hi/lo.

typedef _Float16 f16x8 __attribute__((ext_vector_type(8)));
typedef float f32x4 __attribute__((ext_vector_type(4)));

#define MFMA16(a, b, c_) __builtin_amdgcn_mfma_f32_16x16x32_f16((a), (b), (c_), 0, 0, 0)

#define FLAG_INTS (256 * 64 + 64)  // 256 padded slots + abort word

__device__ __forceinline__ void cvt8(const float4 a, const float4 b, f16x8& hi, f16x8& lo) {
  float v[8] = {a.x, a.y, a.z, a.w, b.x, b.y, b.z, b.w};
#pragma unroll
  for (int j = 0; j < 8; ++j) {
    _Float16 h = (_Float16)v[j];
    hi[j] = h;
    lo[j] = (_Float16)(v[j] - (float)h);
  }
}

// ---------------------------------------------------------------------------
// prep: fragment-ordered fp16 hi|lo buffers. Slot map sigma(h,j)=4h+(j&3)+16*(j>>2),
// same bijection for A and B frags (result independent of HW k-order; R2/R3-verified).
// wf coltile ct = cb*2+cth: col(l15) = (l15>>2)*512 + cb*8 + cth*4 + (l15&3).
// ---------------------------------------------------------------------------
template <bool XPRE>
__global__ void prep_kernel(const float* __restrict__ x, const float* __restrict__ init_h,
                            const float* __restrict__ W_ih, const float* __restrict__ b_ih,
                            const float* __restrict__ W_hh, const float* __restrict__ b_hh,
                            _Float16* __restrict__ xs, _Float16* __restrict__ wf,
                            _Float16* __restrict__ hs, float* __restrict__ bias,
                            int* __restrict__ flags) {
  const long NX = XPRE ? 256L * 512 * 16 * 4 : 0;  // (row,t,ki,h) 8-elem units
  const int NWF = 128 * 34 * 64;                   // (ct,ki,l) 16-f16 units
  const int NH = 256 * 16 * 4;
  long tid = (long)blockIdx.x * 256 + threadIdx.x;

  if (XPRE && tid < NX) {
    int h = tid & 3, ki = (tid >> 2) & 15, t = (tid >> 6) & 511;
    int row = (int)(tid >> 15);
    const float* s = x + (((size_t)row * 512 + t) * 512 + ki * 32 + 4 * h);
    float4 a = *(const float4*)s, b = *(const float4*)(s + 16);
    f16x8 hi, lo;
    cvt8(a, b, hi, lo);
    _Float16* d = xs + ((((size_t)row * 512 + t) * 16 + ki) * 64 + h * 16);
    *(f16x8*)d = hi;
    *(f16x8*)(d + 8) = lo;
    return;
  }
  long u = tid - NX;
  if (u >= 0 && u < NWF) {
    int l = (int)(u & 63);
    int u2 = (int)(u >> 6);
    int ki = u2 % 34, ct = u2 / 34;
    int cb = ct >> 1, cth = ct & 1;
    int l15 = l & 15;
    int col = (l15 >> 2) * 512 + cb * 8 + cth * 4 + (l15 & 3);
    int k = ki * 32 + 4 * (l >> 4);
    float4 a, b;
    if (k < 512) {
      const float* p = W_ih + (size_t)col * 576;
      a = *(const float4*)(p + k);
      b = *(const float4*)(p + k + 16);
    } else if (k < 1024) {
      const float* p = W_hh + (size_t)col * 512;
      a = *(const float4*)(p + k - 512);
      b = *(const float4*)(p + k - 512 + 16);
    } else {
      const float* p = W_ih + (size_t)col * 576 + 512;
      a = *(const float4*)(p + k - 1024);
      b = *(const float4*)(p + k - 1024 + 16);
    }
    f16x8 hi, lo;
    cvt8(a, b, hi, lo);
    _Float16* d = wf + (((size_t)ct * 34 + ki) * 64 + l) * 16;
    *(f16x8*)d = hi;
    *(f16x8*)(d + 8) = lo;
    return;
  }
  u -= NWF;
  if (u >= 0 && u < NH) {
    int h = (int)(u & 3), ki = (int)((u >> 2) & 15), row = (int)(u >> 6);
    const float* s = init_h + ((size_t)row * 512 + ki * 32 + 4 * h);
    float4 a = *(const float4*)s, b = *(const float4*)(s + 16);
    f16x8 hi, lo;
    cvt8(a, b, hi, lo);
    _Float16* d = hs + (((size_t)row * 16 + ki) * 64 + h * 16);  // buffer 0
    *(f16x8*)d = hi;
    *(f16x8*)(d + 8) = lo;
    return;
  }
  u -= NH;
  if (u >= 0 && u < 2048) {
    bias[u] = b_ih[u] + b_hh[u];
    return;
  }
  u -= 2048;
  if (u >= 0 && u < FLAG_INTS) flags[u] = 0;
}

template <bool XPRE>
__global__ void __launch_bounds__(512, 2) recur_kernel(
    const float* __restrict__ x, const float* __restrict__ b_lin,
    const float* __restrict__ W_lin, const _Float16* __restrict__ xs,
    const _Float16* __restrict__ wf, _Float16* __restrict__ hs,
    const float* __restrict__ bias, float* __restrict__ out, float* __restrict__ ylog,
    int* __restrict__ flags) {
  const int p = blockIdx.x;
  const int g = p >> 6, cb = p & 63;
  const int tid = threadIdx.x;
  const int l = tid & 63, w = tid >> 6;
  const int l15 = l & 15, q = l >> 4;
  const int kh = w & 1, cth = (w >> 1) & 1, rtp = w >> 2;  // 2 x 2 x 2 roles

  __shared__ _Float16 wfl[2 * 34 * 64 * 16];   // 139264 B  [cth][ki][l][hi8|lo8]
  __shared__ float pacc[2][2][2][4][64];       // [rtp][cth][tile][reg][lane] 8 KiB
  __shared__ float lp[2][2][16];               // logit partials [rtp][tile][l15]
  __shared__ float wlc[512];                   // W_lin row cb (f32)
  __shared__ int s_ab;

  // ---- one-time staging: wf slice -> LDS, wl col -> LDS ----
  {
    const _Float16* src = wf + (size_t)cb * 2 * 34 * 64 * 16;
#pragma unroll
    for (int i = 0; i < 17; ++i) {
      int idx = tid + i * 512;  // 8704 16B units total
      float4 v = *(const float4*)(src + (size_t)idx * 8);
      *(float4*)(wfl + (size_t)idx * 8) = v;
    }
    if (tid < 512) wlc[tid] = W_lin[(size_t)cb * 512 + tid];
    if (tid == 0) s_ab = 0;
  }
  __syncthreads();

  const float blin = b_lin[cb];
  const int dd = l15 & 3, rr = l15 >> 2;
  const int dglob = cb * 8 + cth * 4 + dd;  // this lane's d (0..511)
  const float bg0 = bias[0 * 512 + dglob];
  const float bg1 = bias[1 * 512 + dglob];
  const float bg2 = bias[2 * 512 + dglob];
  const float bg3 = bias[3 * 512 + dglob];

  const int R0 = g * 64 + rtp * 32;  // tile0 rows R0.., tile1 +16
  const int rowA0 = R0 + l15, rowA1 = R0 + 16 + l15;
  const size_t HSTRIDE = (size_t)256 * 16 * 64;
  const _Float16* hsA0 = hs + (size_t)rowA0 * 1024 + q * 16;
  const _Float16* hsA1 = hs + (size_t)rowA1 * 1024 + q * 16;
  const _Float16* xsA0 = xs + (size_t)rowA0 * 524288 + q * 16;
  const _Float16* xsA1 = xs + (size_t)rowA1 * 524288 + q * 16;
  const float* xfA0 = x + (size_t)rowA0 * 262144 + 4 * q;
  const float* xfA1 = x + (size_t)rowA1 * 262144 + 4 * q;

  const _Float16* wB = wfl + (size_t)cth * 34 * 1024 + (size_t)l * 16;

  // elementwise ownership: lane -> (row = R0 + tile*16 + 4q + rr, d = dglob)
  const int kiH = dglob >> 5, k32 = dglob & 31;
  const int hsl = (k32 & 15) >> 2, jH = (k32 & 3) + 4 * (k32 >> 4);
  const int rowE0 = R0 + 4 * q + rr, rowE1 = rowE0 + 16;
  _Float16* hw0base = hs + ((size_t)rowE0 * 16 + kiH) * 64 + hsl * 16 + jH;
  _Float16* hw1base = hs + ((size_t)rowE1 * 16 + kiH) * 64 + hsl * 16 + jH;

  int* abortf = flags + 256 * 64;

  // Flat-poll flag barrier over the group's 64 blocks. Relaxed polls + one fence
  // (R2-proven ordering: syncthreads drains stores; release-store publishes; fence
  // invalidates before reads). Monotone targets; timeout -> abort (never hangs).
  auto BAR = [&](int target) -> bool {
    __syncthreads();
    if (tid == 0)
      __hip_atomic_store(flags + (size_t)p * 64, target, __ATOMIC_RELEASE,
                         __HIP_MEMORY_SCOPE_AGENT);
    if (tid < 64) {
      int a = 0;
      int* f = flags + ((size_t)g * 64 + tid) * 64;
      int it = 0;
      while (__hip_atomic_load(f, __ATOMIC_RELAXED, __HIP_MEMORY_SCOPE_AGENT) < target) {
        __builtin_amdgcn_s_sleep(1);
        if (++it > 400000) {
          a = 1;
          break;
        }
        if ((it & 255) == 0 &&
            __hip_atomic_load(abortf, __ATOMIC_RELAXED, __HIP_MEMORY_SCOPE_AGENT) != 0) {
          a = 1;
          break;
        }
      }
      a = __any(a) ? 1 : 0;
      if (tid == 0) {
        if (a) __hip_atomic_store(abortf, 1, __ATOMIC_RELAXED, __HIP_MEMORY_SCOPE_AGENT);
        s_ab = a;
      }
      __threadfence();
    }
    __syncthreads();
    return s_ab != 0;
  };

  auto GK = [&](f16x8 ah0, f16x8 al0, f16x8 ah1, f16x8 al1, int ki, f32x4& a0, f32x4& a1) {
    const _Float16* B = wB + (size_t)ki * 1024;
    f16x8 bh = *(const f16x8*)B;
    f16x8 bl = *(const f16x8*)(B + 8);
    a0 = MFMA16(ah0, bh, a0);
    a1 = MFMA16(ah1, bh, a1);
    a0 = MFMA16(al0, bh, a0);
    a1 = MFMA16(al1, bh, a1);
    a0 = MFMA16(ah0, bl, a0);
    a1 = MFMA16(ah1, bl, a1);
  };

  float c0 = 0.f, c1 = 0.f;  // cell state, register-resident for all 512 steps

#pragma unroll 1
  for (int s = 0; s < 512; ++s) {
    f32x4 a0 = {0.f, 0.f, 0.f, 0.f}, a1 = {0.f, 0.f, 0.f, 0.f};

    // ---- x-part (pre-barrier: xs independent of other blocks, L2-warm) ----
    if (XPRE) {
      const _Float16* xA0 = xsA0 + (size_t)s * 1024;
      const _Float16* xA1 = xsA1 + (size_t)s * 1024;
#pragma unroll
      for (int ki = 0; ki < 8; ++ki) {
        int kx = kh * 8 + ki;
        f16x8 ah0 = *(const f16x8*)(xA0 + kx * 64), al0 = *(const f16x8*)(xA0 + kx * 64 + 8);
        f16x8 ah1 = *(const f16x8*)(xA1 + kx * 64), al1 = *(const f16x8*)(xA1 + kx * 64 + 8);
        GK(ah0, al0, ah1, al1, kx, a0, a1);
      }
    } else {
      const float* xp0 = xfA0 + (size_t)s * 512;
      const float* xp1 = xfA1 + (size_t)s * 512;
#pragma unroll 2
      for (int ki = 0; ki < 8; ++ki) {
        int kx = kh * 8 + ki;
        float4 av0 = *(const float4*)(xp0 + kx * 32), bv0 = *(const float4*)(xp0 + kx * 32 + 16);
        float4 av1 = *(const float4*)(xp1 + kx * 32), bv1 = *(const float4*)(xp1 + kx * 32 + 16);
        f16x8 ah0, al0, ah1, al1;
        cvt8(av0, bv0, ah0, al0);
        cvt8(av1, bv1, ah1, al1);
        GK(ah0, al0, ah1, al1, kx, a0, a1);
      }
    }

    // ---- BAR-A: h_{s-1} published by whole group ----
    if (s > 0) {
      if (BAR(2 * s)) return;
    }

    // ---- h-part + fused y-logit dots (col cb), reading h_{s-1} from buf s&1 ----
    float lg0 = 0.f, lg1 = 0.f;
    const _Float16* hA0 = hsA0 + (size_t)(s & 1) * HSTRIDE;
    const _Float16* hA1 = hsA1 + (size_t)(s & 1) * HSTRIDE;
#pragma unroll
    for (int ki = 0; ki < 8; ++ki) {
      int kk = kh * 8 + ki;  // h-k chunk 0..15
      f16x8 ah0 = *(const f16x8*)(hA0 + kk * 64), al0 = *(const f16x8*)(hA0 + kk * 64 + 8);
      f16x8 ah1 = *(const f16x8*)(hA1 + kk * 64), al1 = *(const f16x8*)(hA1 + kk * 64 + 8);
      GK(ah0, al0, ah1, al1, 16 + kk, a0, a1);
      if (cth == 0) {
        float4 wa = *(const float4*)(wlc + kk * 32 + 4 * q);
        float4 wb = *(const float4*)(wlc + kk * 32 + 16 + 4 * q);
        lg0 += ((float)ah0[0] + (float)al0[0]) * wa.x + ((float)ah0[1] + (float)al0[1]) * wa.y +
               ((float)ah0[2] + (float)al0[2]) * wa.z + ((float)ah0[3] + (float)al0[3]) * wa.w +
               ((float)ah0[4] + (float)al0[4]) * wb.x + ((float)ah0[5] + (float)al0[5]) * wb.y +
               ((float)ah0[6] + (float)al0[6]) * wb.z + ((float)ah0[7] + (float)al0[7]) * wb.w;
        lg1 += ((float)ah1[0] + (float)al1[0]) * wa.x + ((float)ah1[1] + (float)al1[1]) * wa.y +
               ((float)ah1[2] + (float)al1[2]) * wa.z + ((float)ah1[3] + (float)al1[3]) * wa.w +
               ((float)ah1[4] + (float)al1[4]) * wb.x + ((float)ah1[5] + (float)al1[5]) * wb.y +
               ((float)ah1[6] + (float)al1[6]) * wb.z + ((float)ah1[7] + (float)al1[7]) * wb.w;
      }
    }

    // ---- logit merge (q-lanes, then K-halves via LDS) + ylog write ----
    if (cth == 0) {
      lg0 += __shfl_xor(lg0, 16);
      lg0 += __shfl_xor(lg0, 32);
      lg1 += __shfl_xor(lg1, 16);
      lg1 += __shfl_xor(lg1, 32);
      if (kh == 1 && l < 16) {
        lp[rtp][0][l15] = lg0;
        lp[rtp][1][l15] = lg1;
      }
    }
    __syncthreads();
    if (cth == 0 && kh == 0 && l < 16) {
      float t0 = lg0 + lp[rtp][0][l15] + blin;
      float t1 = lg1 + lp[rtp][1][l15] + blin;
      float* yb = ylog + ((size_t)g * 64 + cb) * 64;
      yb[rtp * 32 + l15] = t0;
      yb[rtp * 32 + 16 + l15] = t1;
    }

    // ---- BAR-B: ylog(h_{s-1}) complete for the group ----
    if (BAR(2 * s + 1)) return;

    // ---- y-finalize (softmax in registers) + y-kchunk MFMA + out[s-1] ----
    if (s > 0) {
      const float* ybase = ylog + (size_t)g * 64 * 64;
      const bool wr = (cb == 0 && cth == 0 && kh == 0);
#pragma unroll
      for (int t = 0; t < 2; ++t) {
        int rowloc = rtp * 32 + t * 16 + l15;
        float la[4][4];
#pragma unroll
        for (int b2 = 0; b2 < 4; ++b2)
#pragma unroll
          for (int m = 0; m < 4; ++m) la[b2][m] = ybase[(size_t)(16 * b2 + 4 * q + m) * 64 + rowloc];
        float mx = la[0][0];
#pragma unroll
        for (int b2 = 0; b2 < 4; ++b2)
#pragma unroll
          for (int m = 0; m < 4; ++m) mx = fmaxf(mx, la[b2][m]);
        mx = fmaxf(mx, __shfl_xor(mx, 16));
        mx = fmaxf(mx, __shfl_xor(mx, 32));
        float sm = 0.f;
#pragma unroll
        for (int b2 = 0; b2 < 4; ++b2)
#pragma unroll
          for (int m = 0; m < 4; ++m) {
            la[b2][m] = __expf(la[b2][m] - mx);
            sm += la[b2][m];
          }
        sm += __shfl_xor(sm, 16);
        sm += __shfl_xor(sm, 32);
        float inv = 1.f / sm;
        f16x8 yh, yl;
#pragma unroll
        for (int j = 0; j < 8; ++j) {
          float yv = la[(j >> 2) + 2 * kh][j & 3] * inv;
          _Float16 hh = (_Float16)yv;
          yh[j] = hh;
          yl[j] = (_Float16)(yv - (float)hh);
        }
        if (wr) {
          size_t ob = ((size_t)(g * 64 + rowloc) * 512 + (s - 1)) * 64;
#pragma unroll
          for (int b2 = 0; b2 < 4; ++b2)
#pragma unroll
            for (int m = 0; m < 4; ++m) out[ob + 16 * b2 + 4 * q + m] = la[b2][m] * inv;
        }
        const _Float16* B = wB + (size_t)(32 + kh) * 1024;
        f16x8 bh = *(const f16x8*)B;
        f16x8 bl = *(const f16x8*)(B + 8);
        f32x4& at = (t == 0) ? a0 : a1;
        at = MFMA16(yh, bh, at);
        at = MFMA16(yl, bh, at);
        at = MFMA16(yh, bl, at);
      }
    }

    // ---- K-half merge of gate pre-activations ----
    if (kh == 1) {
#pragma unroll
      for (int r = 0; r < 4; ++r) {
        pacc[rtp][cth][0][r][l] = a0[r];
        pacc[rtp][cth][1][r][l] = a1[r];
      }
    }
    __syncthreads();
    if (kh == 0) {
#pragma unroll
      for (int r = 0; r < 4; ++r) {
        a0[r] += pacc[rtp][cth][0][r][l];
        a1[r] += pacc[rtp][cth][1][r][l];
      }
      // ---- elementwise LSTM (lane owns (row, dglob) per tile) + h-store ----
      const int wbuf = (s + 1) & 1;
#pragma unroll
      for (int t = 0; t < 2; ++t) {
        float z[4];
#pragma unroll
        for (int gi = 0; gi < 4; ++gi) {
          int src = (l & 48) | (gi * 4 + dd);
          float v0, v1, v2, v3;
          if (t == 0) {
            v0 = __shfl(a0[0], src);
            v1 = __shfl(a0[1], src);
            v2 = __shfl(a0[2], src);
            v3 = __shfl(a0[3], src);
          } else {
            v0 = __shfl(a1[0], src);
            v1 = __shfl(a1[1], src);
            v2 = __shfl(a1[2], src);
            v3 = __shfl(a1[3], src);
          }
          z[gi] = (rr == 0) ? v0 : (rr == 1) ? v1 : (rr == 2) ? v2 : v3;
        }
        float zi = z[0] + bg0, zf = z[1] + bg1, zg = z[2] + bg2, zo = z[3] + bg3;
        float iv = 1.f / (1.f + __expf(-zi));
        float fv = 1.f / (1.f + __expf(-zf));
        float eg = __expf(2.f * zg);
        float gv = 1.f - 2.f / (eg + 1.f);
        float ov = 1.f / (1.f + __expf(-zo));
        float cc = (t == 0) ? c0 : c1;
        float cn = fv * cc + iv * gv;
        if (t == 0)
          c0 = cn;
        else
          c1 = cn;
        float ec = __expf(2.f * cn);
        float th = 1.f - 2.f / (ec + 1.f);
        float hv = ov * th;
        _Float16 hh = (_Float16)hv;
        _Float16 hl = (_Float16)(hv - (float)hh);
        _Float16* hw = ((t == 0) ? hw0base : hw1base) + (size_t)wbuf * HSTRIDE;
        hw[0] = hh;
        hw[8] = hl;
      }
    }
  }

  // ---- epilogue: y_511 = softmax(h_511 . W_lin) -> out[511] ----
  if (BAR(1024)) return;
  {
    float lg0 = 0.f, lg1 = 0.f;
    const _Float16* hA0 = hsA0;  // h_511 lives in buffer 0 (512 & 1 == 0)
    const _Float16* hA1 = hsA1;
    if (cth == 0) {
#pragma unroll
      for (int ki = 0; ki < 8; ++ki) {
        int kk = kh * 8 + ki;
        f16x8 ah0 = *(const f16x8*)(hA0 + kk * 64), al0 = *(const f16x8*)(hA0 + kk * 64 + 8);
        f16x8 ah1 = *(const f16x8*)(hA1 + kk * 64), al1 = *(const f16x8*)(hA1 + kk * 64 + 8);
        float4 wa = *(const float4*)(wlc + kk * 32 + 4 * q);
        float4 wb = *(const float4*)(wlc + kk * 32 + 16 + 4 * q);
        lg0 += ((float)ah0[0] + (float)al0[0]) * wa.x + ((float)ah0[1] + (float)al0[1]) * wa.y +
               ((float)ah0[2] + (float)al0[2]) * wa.z + ((float)ah0[3] + (float)al0[3]) * wa.w +
               ((float)ah0[4] + (float)al0[4]) * wb.x + ((float)ah0[5] + (float)al0[5]) * wb.y +
               ((float)ah0[6] + (float)al0[6]) * wb.z + ((float)ah0[7] + (float)al0[7]) * wb.w;
        lg1 += ((float)ah1[0] + (float)al1[0]) * wa.x + ((float)ah1[1] + (float)al1[1]) * wa.y +
               ((float)ah1[2] + (float)al1[2]) * wa.z + ((float)ah1[3] + (float)al1[3]) * wa.w +
               ((float)ah1[4] + (float)al1[4]) * wb.x + ((float)ah1[5] + (float)al1[5]) * wb.y +
               ((float)ah1[6] + (float)al1[6]) * wb.z + ((float)ah1[7] + (float)al1[7]) * wb.w;
      }
      lg0 += __shfl_xor(lg0, 16);
      lg0 += __shfl_xor(lg0, 32);
      lg1 += __shfl_xor(lg1, 16);
      lg1 += __shfl_xor(lg1, 32);
      if (kh == 1 && l < 16) {
        lp[rtp][0][l15] = lg0;
        lp[rtp][1][l15] = lg1;
      }
    }
    __syncthreads();
    if (cth == 0 && kh == 0 && l < 16) {
      float* yb = ylog + ((size_t)g * 64 + cb) * 64;
      yb[rtp * 32 + l15] = lg0 + lp[rtp][0][l15] + blin;
      yb[rtp * 32 + 16 + l15] = lg1 + lp[rtp][1][l15] + blin;
    }
  }
  if (BAR(1025)) return;
  if (cb == 0 && cth == 0 && kh == 0) {
    const float* ybase = ylog + (size_t)g * 64 * 64;
#pragma unroll
    for (int t = 0; t < 2; ++t) {
      int rowloc = rtp * 32 + t * 16 + l15;
      float la[4][4];
#pragma unroll
      for (int b2 = 0; b2 < 4; ++b2)
#pragma unroll
        for (int m = 0; m < 4; ++m) la[b2][m] = ybase[(size_t)(16 * b2 + 4 * q + m) * 64 + rowloc];
      float mx = la[0][0];
#pragma unroll
      for (int b2 = 0; b2 < 4; ++b2)
#pragma unroll
        for (int m = 0; m < 4; ++m) mx = fmaxf(mx, la[b2][m]);
      mx = fmaxf(mx, __shfl_xor(mx, 16));
      mx = fmaxf(mx, __shfl_xor(mx, 32));
      float sm = 0.f;
#pragma unroll
      for (int b2 = 0; b2 < 4; ++b2)
#pragma unroll
        for (int m = 0; m < 4; ++m) {
          la[b2][m] = __expf(la[b2][m] - mx);
          sm += la[b2][m];
        }
      sm += __shfl_xor(sm, 16);
      sm += __shfl_xor(sm, 32);
      float inv = 1.f / sm;
      size_t ob = ((size_t)(g * 64 + rowloc) * 512 + 511) * 64;
#pragma unroll
      for (int b2 = 0; b2 < 4; ++b2)
#pragma unroll
        for (int m = 0; m < 4; ++m) out[ob + 16 * b2 + 4 * q + m] = la[b2][m] * inv;
    }
  }
}

extern "C" void kernel_launch(void* const* d_in, const int* in_sizes, int n_in, void* d_out,
                              int out_size, void* d_ws, size_t ws_size, hipStream_t stream) {
  const float* x = (const float*)d_in[0];
  const float* init_h = (const float*)d_in[1];
  const float* W_ih = (const float*)d_in[2];
  const float* b_ih = (const float*)d_in[3];
  const float* W_hh = (const float*)d_in[4];
  const float* b_hh = (const float*)d_in[5];
  const float* W_lin = (const float*)d_in[6];
  const float* b_lin = (const float*)d_in[7];
  float* out = (float*)d_out;
  (void)in_sizes;
  (void)n_in;
  (void)out_size;

  char* ws = (char*)d_ws;
  size_t off = 0;
  auto take = [&](size_t bytes) -> char* {
    char* r = ws + off;
    off = (off + bytes + 255) & ~(size_t)255;
    return r;
  };
  const size_t WF_E = (size_t)128 * 34 * 64 * 16;   // f16 elems (hi|lo packed)
  const size_t HS_E = (size_t)2 * 256 * 16 * 64;    // double-buffered h frags
  const size_t XS_E = (size_t)256 * 512 * 16 * 64;  // pre-split x frags

  _Float16* wf = (_Float16*)take(WF_E * 2);
  _Float16* hs = (_Float16*)take(HS_E * 2);
  float* bias = (float*)take(2048 * 4);
  float* ylogb = (float*)take((size_t)4 * 64 * 64 * 4);
  int* flags = (int*)take((size_t)FLAG_INTS * 4);
  if (ws_size < off) return;  // cannot run -> visible failure
  _Float16* xs = (_Float16*)(ws + off);
  const bool xpre = (ws_size >= off + XS_E * 2);

  if (xpre) {
    const long total = 8388608L + 278528 + 16384 + 2048 + FLAG_INTS;
    prep_kernel<true><<<(int)((total + 255) / 256), 256, 0, stream>>>(
        x, init_h, W_ih, b_ih, W_hh, b_hh, xs, wf, hs, bias, flags);
    recur_kernel<true><<<256, 512, 0, stream>>>(x, b_lin, W_lin, xs, wf, hs, bias, out, ylogb,
                                                flags);
  } else {
    const long total = 278528L + 16384 + 2048 + FLAG_INTS;
    prep_kernel<false><<<(int)((total + 255) / 256), 256, 0, stream>>>(
        x, init_h, W_ih, b_ih, W_hh, b_hh, xs, wf, hs, bias, flags);
    recur_kernel<false><<<256, 512, 0, stream>>>(x, b_lin, W_lin, xs, wf, hs, bias, out, ylogb,
                                                 flags);
  }
}

// Round 5
// 9496.064 us; speedup vs baseline: 2.0626x; 1.9951x over previous
//
#include <hip/hip_runtime.h>
#include <cstdint>
#include <cstddef>

// Autoregressive LSTM cell with softmax feedback. B=256, T=512, D=512, N=64.
// R5: ZERO cache-maintenance design. R2-R4 all pinned at ~37us/step because every
// step executed agent-scope release/acquire fences (wbl2 + L2-invalidate): partial
// dirty-line writebacks (5.8GB WRITE_SIZE, cross-XCD false sharing on h lines) and
// full working-set re-streams from LLC after each invalidate.
// Fix: ALL cross-block data (h, ylog, flags) moves via RELAXED agent-scope atomics
// (HW-routed to LLC; never dirty in L2, never stale in L2). Ordering via vmcnt drain
// (__syncthreads) before flag store. No RELEASE, no __threadfence anywhere in the loop
// -> weights-in-LDS and the x-fragment stream stay cached.
// h packed short2(hi,lo) = 4B/elem: one u32 atomic store per element, u64 atomic
// fragment loads. 256 blocks x 512 thr (8 waves = 4 row-tiles x 2 K-halves), 1/CU.
// y-logits: fused fp32 VALU dots (block owns y-col cb) + shfl/LDS merge -> 256B ylog
// -> BAR-B -> in-register softmax -> fp16 y-frags. Numerics: fp16 hi/lo 3-pass gates.

typedef _Float16 f16x8 __attribute__((ext_vector_type(8)));
typedef float f32x4 __attribute__((ext_vector_type(4)));

#define MFMA16(a, b, c_) __builtin_amdgcn_mfma_f32_16x16x32_f16((a), (b), (c_), 0, 0, 0)
#define AGT __HIP_MEMORY_SCOPE_AGENT
#define RLX __ATOMIC_RELAXED

#define FLAG_INTS (256 * 64 + 64)  // 256 padded flag slots + abort word
#define HS2_U32 131072             // per h buffer: 256 rows * 512 u32 (short2 per elem)

static __device__ __forceinline__ unsigned short f2b(_Float16 h) {
  return __builtin_bit_cast(unsigned short, h);
}
static __device__ __forceinline__ _Float16 b2f(unsigned short s) {
  return __builtin_bit_cast(_Float16, s);
}

__device__ __forceinline__ void cvt8(const float4 a, const float4 b, f16x8& hi, f16x8& lo) {
  float v[8] = {a.x, a.y, a.z, a.w, b.x, b.y, b.z, b.w};
#pragma unroll
  for (int j = 0; j < 8; ++j) {
    _Float16 h = (_Float16)v[j];
    hi[j] = h;
    lo[j] = (_Float16)(v[j] - (float)h);
  }
}

// ---------------------------------------------------------------------------
// prep. Slot map sigma(q,j)=4q+(j&3)+16*(j>>2), same bijection on A and B frags
// (R2-R4 verified). wf global layout identical to R4: ct=cb*2+cth,
// col(l15) = (l15>>2)*512 + cb*8 + cth*4 + (l15&3).
// hs2: buffer0 = init_h, packed u32 = lo16:hi16 = (fp16_hi | fp16_lo<<16).
// ---------------------------------------------------------------------------
template <bool XPRE>
__global__ void prep_kernel(const float* __restrict__ x, const float* __restrict__ init_h,
                            const float* __restrict__ W_ih, const float* __restrict__ b_ih,
                            const float* __restrict__ W_hh, const float* __restrict__ b_hh,
                            _Float16* __restrict__ xs, _Float16* __restrict__ wf,
                            unsigned int* __restrict__ hs2, float* __restrict__ bias,
                            int* __restrict__ flags) {
  const long NX = XPRE ? 256L * 512 * 16 * 4 : 0;  // (row,t,ki,q) 8-elem units
  const int NWF = 128 * 34 * 64;                   // (ct,ki,l) 16-f16 units
  const int NH2 = 256 * 16 * 4;                    // (row,ki,q) 8-elem units
  long tid = (long)blockIdx.x * 256 + threadIdx.x;

  if (XPRE && tid < NX) {
    int q = tid & 3, ki = (tid >> 2) & 15, t = (tid >> 6) & 511;
    int row = (int)(tid >> 15);
    const float* s = x + (((size_t)row * 512 + t) * 512 + ki * 32 + 4 * q);
    float4 a = *(const float4*)s, b = *(const float4*)(s + 16);
    f16x8 hi, lo;
    cvt8(a, b, hi, lo);
    _Float16* d = xs + ((((size_t)row * 512 + t) * 16 + ki) * 64 + q * 16);
    *(f16x8*)d = hi;
    *(f16x8*)(d + 8) = lo;
    return;
  }
  long u = tid - NX;
  if (u >= 0 && u < NWF) {
    int l = (int)(u & 63);
    int u2 = (int)(u >> 6);
    int ki = u2 % 34, ct = u2 / 34;
    int cb = ct >> 1, cth = ct & 1;
    int l15 = l & 15;
    int col = (l15 >> 2) * 512 + cb * 8 + cth * 4 + (l15 & 3);
    int k = ki * 32 + 4 * (l >> 4);
    float4 a, b;
    if (k < 512) {
      const float* p = W_ih + (size_t)col * 576;
      a = *(const float4*)(p + k);
      b = *(const float4*)(p + k + 16);
    } else if (k < 1024) {
      const float* p = W_hh + (size_t)col * 512;
      a = *(const float4*)(p + k - 512);
      b = *(const float4*)(p + k - 512 + 16);
    } else {
      const float* p = W_ih + (size_t)col * 576 + 512;
      a = *(const float4*)(p + k - 1024);
      b = *(const float4*)(p + k - 1024 + 16);
    }
    f16x8 hi, lo;
    cvt8(a, b, hi, lo);
    _Float16* d = wf + (((size_t)ct * 34 + ki) * 64 + l) * 16;
    *(f16x8*)d = hi;
    *(f16x8*)(d + 8) = lo;
    return;
  }
  u -= NWF;
  if (u >= 0 && u < NH2) {
    int q = (int)(u & 3), ki = (int)((u >> 2) & 15), row = (int)(u >> 6);
    const float* s = init_h + ((size_t)row * 512 + ki * 32 + 4 * q);
    float4 a = *(const float4*)s, b = *(const float4*)(s + 16);
    float v[8] = {a.x, a.y, a.z, a.w, b.x, b.y, b.z, b.w};
    unsigned int pk[8];
#pragma unroll
    for (int j = 0; j < 8; ++j) {
      _Float16 hh = (_Float16)v[j];
      _Float16 hl = (_Float16)(v[j] - (float)hh);
      pk[j] = (unsigned int)f2b(hh) | ((unsigned int)f2b(hl) << 16);
    }
    unsigned int* base = hs2 + ((size_t)row * 16 + ki) * 32;  // buffer 0
    *(uint4*)(base + 4 * q) = make_uint4(pk[0], pk[1], pk[2], pk[3]);
    *(uint4*)(base + 16 + 4 * q) = make_uint4(pk[4], pk[5], pk[6], pk[7]);
    return;
  }
  u -= NH2;
  if (u >= 0 && u < 2048) {
    bias[u] = b_ih[u] + b_hh[u];
    return;
  }
  u -= 2048;
  if (u >= 0 && u < FLAG_INTS) flags[u] = 0;
}

// one k-chunk, both cth col-tiles: 6 MFMAs (3-pass hi/lo)
#define GKSTEP(AH, AL, KI)                                                   \
  {                                                                          \
    const _Float16* B0p = wfl + (size_t)(KI)*1024 + (size_t)l * 16;          \
    const _Float16* B1p = B0p + 34 * 1024;                                   \
    f16x8 b0h = *(const f16x8*)B0p, b0l = *(const f16x8*)(B0p + 8);          \
    f16x8 b1h = *(const f16x8*)B1p, b1l = *(const f16x8*)(B1p + 8);          \
    aC0 = MFMA16((AH), b0h, aC0);                                            \
    aC1 = MFMA16((AH), b1h, aC1);                                            \
    aC0 = MFMA16((AL), b0h, aC0);                                            \
    aC1 = MFMA16((AL), b1h, aC1);                                            \
    aC0 = MFMA16((AH), b0l, aC0);                                            \
    aC1 = MFMA16((AH), b1l, aC1);                                            \
  }

template <bool XPRE>
__global__ void __launch_bounds__(512, 2) recur_kernel(
    const float* __restrict__ x, const float* __restrict__ b_lin,
    const float* __restrict__ W_lin, const _Float16* __restrict__ xs,
    const _Float16* __restrict__ wf, unsigned int* __restrict__ hs2,
    const float* __restrict__ bias, float* __restrict__ out, float* __restrict__ ylog,
    int* __restrict__ flags) {
  const int bid = blockIdx.x;
  const int x8 = bid & 7;                       // XCD under round-robin dispatch
  const int g = x8 >> 1;                        // group g on XCD pair {2g, 2g+1}
  const int cb = (x8 & 1) * 32 + (bid >> 3);    // 0..63: block's 8-d column slice
  const int tid = threadIdx.x;
  const int l = tid & 63, w = tid >> 6;
  const int l15 = l & 15, q = l >> 4;
  const int kh = w & 1, rtp = w >> 1;           // 2 K-halves x 4 row-tiles

  __shared__ _Float16 wfl[2 * 34 * 64 * 16];    // 136 KiB weight slice (hi|lo frags)
  __shared__ float pacc[4][2][4][64];           // K-half merge of gate accums (8 KiB)
  __shared__ float lp[4][16];                   // K-half merge of y-logit dots
  __shared__ int s_ab;

  {  // one-time LDS staging
    const _Float16* srcw = wf + (size_t)cb * (2 * 34 * 64 * 16);
#pragma unroll
    for (int i = 0; i < 17; ++i) {
      int idx = tid + i * 512;
      *(float4*)(wfl + (size_t)idx * 8) = *(const float4*)(srcw + (size_t)idx * 8);
    }
    if (tid == 0) s_ab = 0;
  }
  __syncthreads();

  const int dd = l15 & 3, rr = l15 >> 2;
  float bg[2][4];
#pragma unroll
  for (int c2 = 0; c2 < 2; ++c2)
#pragma unroll
    for (int gi = 0; gi < 4; ++gi) bg[c2][gi] = bias[gi * 512 + cb * 8 + c2 * 4 + dd];
  const float blin = b_lin[cb];

  const int Rw = g * 64 + rtp * 16;
  const int rowA = Rw + l15;
  const int hoff = rowA * 512 + 4 * q;  // u32 offset; + ki*32 (+16)
  const _Float16* xsA = xs + (size_t)rowA * 524288 + q * 16;
  const float* xfA = x + (size_t)rowA * 262144 + 4 * q;
  const float* wl = W_lin + (size_t)cb * 512;

  const int rowE = Rw + 4 * q + rr;
  unsigned int hwo[2];
#pragma unroll
  for (int c2 = 0; c2 < 2; ++c2) {
    int dglob = cb * 8 + c2 * 4 + dd;
    int kiH = dglob >> 5, k32 = dglob & 31;
    int e = 4 * ((k32 & 15) >> 2) + (k32 & 3) + 16 * (k32 >> 4);
    hwo[c2] = (unsigned int)((rowE * 16 + kiH) * 32 + e);
  }

  int* abortf = flags + 256 * 64;

  // Relaxed flag barrier over the group's 64 blocks. NO fences: __syncthreads
  // drains vmcnt (atomic stores acked at LLC) before the flag store; all shared
  // data is itself LLC-routed atomics. Timeout -> abort flag -> visible failure.
  auto BAR = [&](int target) -> bool {
    __syncthreads();
    if (tid == 0)
      __hip_atomic_store(flags + (size_t)(g * 64 + cb) * 64, target, RLX, AGT);
    if (tid < 64) {
      int a = 0;
      int* f = flags + ((size_t)g * 64 + tid) * 64;
      int it = 0;
      while (__hip_atomic_load(f, RLX, AGT) < target) {
        __builtin_amdgcn_s_sleep(1);
        if (++it > 400000) {
          a = 1;
          break;
        }
        if ((it & 255) == 0 && __hip_atomic_load(abortf, RLX, AGT) != 0) {
          a = 1;
          break;
        }
      }
      a = __any(a) ? 1 : 0;
      if (tid == 0) {
        if (a) __hip_atomic_store(abortf, 1, RLX, AGT);
        s_ab = a;
      }
    }
    __syncthreads();
    return s_ab != 0;
  };

  float cst[2] = {0.f, 0.f};  // cell state in registers all 512 steps
  f32x4 aC0, aC1;

#pragma unroll 1
  for (int s = 0; s < 512; ++s) {
    aC0 = (f32x4){0.f, 0.f, 0.f, 0.f};
    aC1 = (f32x4){0.f, 0.f, 0.f, 0.f};

    // ---- x-part (plain cached loads; never invalidated) ----
    if (XPRE) {
      const _Float16* xA = xsA + (size_t)s * 1024;
#pragma unroll
      for (int i = 0; i < 8; ++i) {
        int kx = kh * 8 + i;
        f16x8 ah = *(const f16x8*)(xA + kx * 64);
        f16x8 al = *(const f16x8*)(xA + kx * 64 + 8);
        GKSTEP(ah, al, kx);
      }
    } else {
      const float* xp = xfA + (size_t)s * 512;
#pragma unroll 2
      for (int i = 0; i < 8; ++i) {
        int kx = kh * 8 + i;
        float4 av = *(const float4*)(xp + kx * 32);
        float4 bv = *(const float4*)(xp + kx * 32 + 16);
        f16x8 ah, al;
        cvt8(av, bv, ah, al);
        GKSTEP(ah, al, kx);
      }
    }

    // ---- BAR-A: h_{s-1} published (s=0 reads prep-written buffer 0) ----
    if (s > 0) {
      if (BAR(2 * s)) return;
    }

    // ---- h-part (u64 LLC atomic loads) + fused y-logit dots ----
    const unsigned int* hp0 = hs2 + (size_t)(s & 1) * HS2_U32 + hoff;
    float dlg = 0.f;
#pragma unroll
    for (int i = 0; i < 8; ++i) {
      int kk = kh * 8 + i;
      const unsigned int* hp = hp0 + kk * 32;
      unsigned long long u0 = __hip_atomic_load((const unsigned long long*)hp, RLX, AGT);
      unsigned long long u1 = __hip_atomic_load((const unsigned long long*)(hp + 2), RLX, AGT);
      unsigned long long u2 = __hip_atomic_load((const unsigned long long*)(hp + 16), RLX, AGT);
      unsigned long long u3 = __hip_atomic_load((const unsigned long long*)(hp + 18), RLX, AGT);
      unsigned int wd[8] = {(unsigned int)u0, (unsigned int)(u0 >> 32),
                            (unsigned int)u1, (unsigned int)(u1 >> 32),
                            (unsigned int)u2, (unsigned int)(u2 >> 32),
                            (unsigned int)u3, (unsigned int)(u3 >> 32)};
      f16x8 ah, al;
#pragma unroll
      for (int j = 0; j < 8; ++j) {
        ah[j] = b2f((unsigned short)(wd[j] & 0xffffu));
        al[j] = b2f((unsigned short)(wd[j] >> 16));
      }
      GKSTEP(ah, al, 16 + kk);
      float4 wa = *(const float4*)(wl + kk * 32 + 4 * q);
      float4 wb2 = *(const float4*)(wl + kk * 32 + 16 + 4 * q);
      dlg += ((float)ah[0] + (float)al[0]) * wa.x + ((float)ah[1] + (float)al[1]) * wa.y +
             ((float)ah[2] + (float)al[2]) * wa.z + ((float)ah[3] + (float)al[3]) * wa.w +
             ((float)ah[4] + (float)al[4]) * wb2.x + ((float)ah[5] + (float)al[5]) * wb2.y +
             ((float)ah[6] + (float)al[6]) * wb2.z + ((float)ah[7] + (float)al[7]) * wb2.w;
    }
    dlg += __shfl_xor(dlg, 16);
    dlg += __shfl_xor(dlg, 32);
    if (kh == 1 && l < 16) lp[rtp][l15] = dlg;
    __syncthreads();
    if (kh == 0 && l < 16) {
      float full = dlg + lp[rtp][l15] + blin;
      __hip_atomic_store(ylog + ((size_t)g * 64 + cb) * 64 + rtp * 16 + l15, full, RLX, AGT);
    }

    // ---- BAR-B: ylog(h_{s-1}) complete ----
    if (BAR(2 * s + 1)) return;

    // ---- y softmax (in registers) + y-feedback MFMA + out[s-1] ----
    if (s > 0) {
      float la[4][4];
#pragma unroll
      for (int b2 = 0; b2 < 4; ++b2)
#pragma unroll
        for (int m = 0; m < 4; ++m)
          la[b2][m] = __hip_atomic_load(
              ylog + ((size_t)g * 64 + 16 * b2 + 4 * q + m) * 64 + rtp * 16 + l15, RLX, AGT);
      float mx = la[0][0];
#pragma unroll
      for (int b2 = 0; b2 < 4; ++b2)
#pragma unroll
        for (int m = 0; m < 4; ++m) mx = fmaxf(mx, la[b2][m]);
      mx = fmaxf(mx, __shfl_xor(mx, 16));
      mx = fmaxf(mx, __shfl_xor(mx, 32));
      float sm = 0.f;
#pragma unroll
      for (int b2 = 0; b2 < 4; ++b2)
#pragma unroll
        for (int m = 0; m < 4; ++m) {
          la[b2][m] = __expf(la[b2][m] - mx);
          sm += la[b2][m];
        }
      sm += __shfl_xor(sm, 16);
      sm += __shfl_xor(sm, 32);
      float inv = 1.f / sm;
      if (cb == 0 && kh == 0) {
        size_t ob = (((size_t)(g * 64 + rtp * 16 + l15)) * 512 + (s - 1)) * 64;
#pragma unroll
        for (int b2 = 0; b2 < 4; ++b2)
#pragma unroll
          for (int m = 0; m < 4; ++m) out[ob + 16 * b2 + 4 * q + m] = la[b2][m] * inv;
      }
      f16x8 yh;
      if (kh == 0) {
#pragma unroll
        for (int j = 0; j < 8; ++j) yh[j] = (_Float16)(la[j >> 2][j & 3] * inv);
      } else {
#pragma unroll
        for (int j = 0; j < 8; ++j) yh[j] = (_Float16)(la[(j >> 2) + 2][j & 3] * inv);
      }
      const _Float16* B0p = wfl + (size_t)(32 + kh) * 1024 + (size_t)l * 16;
      const _Float16* B1p = B0p + 34 * 1024;
      f16x8 b0h = *(const f16x8*)B0p, b0l = *(const f16x8*)(B0p + 8);
      f16x8 b1h = *(const f16x8*)B1p, b1l = *(const f16x8*)(B1p + 8);
      aC0 = MFMA16(yh, b0h, aC0);
      aC1 = MFMA16(yh, b1h, aC1);
      aC0 = MFMA16(yh, b0l, aC0);
      aC1 = MFMA16(yh, b1l, aC1);
    }

    // ---- K-half merge ----
    if (kh == 1) {
#pragma unroll
      for (int r = 0; r < 4; ++r) {
        pacc[rtp][0][r][l] = aC0[r];
        pacc[rtp][1][r][l] = aC1[r];
      }
    }
    __syncthreads();
    if (kh == 0) {
#pragma unroll
      for (int r = 0; r < 4; ++r) {
        aC0[r] += pacc[rtp][0][r][l];
        aC1[r] += pacc[rtp][1][r][l];
      }
      // ---- elementwise LSTM + packed h atomic store ----
      const unsigned int wb_ = (unsigned int)(((s & 1) ^ 1) * HS2_U32);
#pragma unroll
      for (int c2 = 0; c2 < 2; ++c2) {
        f32x4 A = c2 ? aC1 : aC0;
        float z[4];
#pragma unroll
        for (int gi = 0; gi < 4; ++gi) {
          int src = (l & 48) | (gi * 4 + dd);
          float v0 = __shfl(A[0], src), v1 = __shfl(A[1], src);
          float v2 = __shfl(A[2], src), v3 = __shfl(A[3], src);
          z[gi] = (rr == 0) ? v0 : (rr == 1) ? v1 : (rr == 2) ? v2 : v3;
        }
        float zi = z[0] + bg[c2][0], zf = z[1] + bg[c2][1];
        float zg = z[2] + bg[c2][2], zo = z[3] + bg[c2][3];
        float iv = 1.f / (1.f + __expf(-zi));
        float fv = 1.f / (1.f + __expf(-zf));
        float eg = __expf(2.f * zg);
        float gv = 1.f - 2.f / (eg + 1.f);
        float ov = 1.f / (1.f + __expf(-zo));
        float cn = fv * cst[c2] + iv * gv;
        cst[c2] = cn;
        float ec = __expf(2.f * cn);
        float th = 1.f - 2.f / (ec + 1.f);
        float hv = ov * th;
        _Float16 hh = (_Float16)hv;
        _Float16 hl = (_Float16)(hv - (float)hh);
        unsigned int pk = (unsigned int)f2b(hh) | ((unsigned int)f2b(hl) << 16);
        __hip_atomic_store(hs2 + wb_ + hwo[c2], pk, RLX, AGT);
      }
    }
  }

  // ---- epilogue: y_511 from h_511 (buffer 0) ----
  if (BAR(1024)) return;
  {
    const unsigned int* hp0 = hs2 + hoff;  // buffer 0
    float dlg = 0.f;
#pragma unroll
    for (int i = 0; i < 8; ++i) {
      int kk = kh * 8 + i;
      const unsigned int* hp = hp0 + kk * 32;
      unsigned long long u0 = __hip_atomic_load((const unsigned long long*)hp, RLX, AGT);
      unsigned long long u1 = __hip_atomic_load((const unsigned long long*)(hp + 2), RLX, AGT);
      unsigned long long u2 = __hip_atomic_load((const unsigned long long*)(hp + 16), RLX, AGT);
      unsigned long long u3 = __hip_atomic_load((const unsigned long long*)(hp + 18), RLX, AGT);
      unsigned int wd[8] = {(unsigned int)u0, (unsigned int)(u0 >> 32),
                            (unsigned int)u1, (unsigned int)(u1 >> 32),
                            (unsigned int)u2, (unsigned int)(u2 >> 32),
                            (unsigned int)u3, (unsigned int)(u3 >> 32)};
      float4 wa = *(const float4*)(wl + kk * 32 + 4 * q);
      float4 wb2 = *(const float4*)(wl + kk * 32 + 16 + 4 * q);
      float hv0[8];
#pragma unroll
      for (int j = 0; j < 8; ++j)
        hv0[j] = (float)b2f((unsigned short)(wd[j] & 0xffffu)) +
                 (float)b2f((unsigned short)(wd[j] >> 16));
      dlg += hv0[0] * wa.x + hv0[1] * wa.y + hv0[2] * wa.z + hv0[3] * wa.w + hv0[4] * wb2.x +
             hv0[5] * wb2.y + hv0[6] * wb2.z + hv0[7] * wb2.w;
    }
    dlg += __shfl_xor(dlg, 16);
    dlg += __shfl_xor(dlg, 32);
    if (kh == 1 && l < 16) lp[rtp][l15] = dlg;
    __syncthreads();
    if (kh == 0 && l < 16)
      __hip_atomic_store(ylog + ((size_t)g * 64 + cb) * 64 + rtp * 16 + l15,
                         dlg + lp[rtp][l15] + blin, RLX, AGT);
  }
  if (BAR(1025)) return;
  if (cb == 0 && kh == 0) {
    float la[4][4];
#pragma unroll
    for (int b2 = 0; b2 < 4; ++b2)
#pragma unroll
      for (int m = 0; m < 4; ++m)
        la[b2][m] = __hip_atomic_load(
            ylog + ((size_t)g * 64 + 16 * b2 + 4 * q + m) * 64 + rtp * 16 + l15, RLX, AGT);
    float mx = la[0][0];
#pragma unroll
    for (int b2 = 0; b2 < 4; ++b2)
#pragma unroll
      for (int m = 0; m < 4; ++m) mx = fmaxf(mx, la[b2][m]);
    mx = fmaxf(mx, __shfl_xor(mx, 16));
    mx = fmaxf(mx, __shfl_xor(mx, 32));
    float sm = 0.f;
#pragma unroll
    for (int b2 = 0; b2 < 4; ++b2)
#pragma unroll
      for (int m = 0; m < 4; ++m) {
        la[b2][m] = __expf(la[b2][m] - mx);
        sm += la[b2][m];
      }
    sm += __shfl_xor(sm, 16);
    sm += __shfl_xor(sm, 32);
    float inv = 1.f / sm;
    size_t ob = (((size_t)(g * 64 + rtp * 16 + l15)) * 512 + 511) * 64;
#pragma unroll
    for (int b2 = 0; b2 < 4; ++b2)
#pragma unroll
      for (int m = 0; m < 4; ++m) out[ob + 16 * b2 + 4 * q + m] = la[b2][m] * inv;
  }
}

extern "C" void kernel_launch(void* const* d_in, const int* in_sizes, int n_in, void* d_out,
                              int out_size, void* d_ws, size_t ws_size, hipStream_t stream) {
  const float* x = (const float*)d_in[0];
  const float* init_h = (const float*)d_in[1];
  const float* W_ih = (const float*)d_in[2];
  const float* b_ih = (const float*)d_in[3];
  const float* W_hh = (const float*)d_in[4];
  const float* b_hh = (const float*)d_in[5];
  const float* W_lin = (const float*)d_in[6];
  const float* b_lin = (const float*)d_in[7];
  float* out = (float*)d_out;
  (void)in_sizes;
  (void)n_in;
  (void)out_size;

  char* ws = (char*)d_ws;
  size_t off = 0;
  auto take = [&](size_t bytes) -> char* {
    char* r = ws + off;
    off = (off + bytes + 255) & ~(size_t)255;
    return r;
  };
  const size_t WF_E = (size_t)128 * 34 * 64 * 16;   // f16 elems
  const size_t XS_E = (size_t)256 * 512 * 16 * 64;  // f16 elems

  _Float16* wf = (_Float16*)take(WF_E * 2);
  unsigned int* hs2 = (unsigned int*)take((size_t)2 * HS2_U32 * 4);
  float* bias = (float*)take(2048 * 4);
  float* ylogb = (float*)take((size_t)4 * 64 * 64 * 4);
  int* flags = (int*)take((size_t)FLAG_INTS * 4);
  if (ws_size < off) return;  // cannot run -> visible failure
  _Float16* xs = (_Float16*)(ws + off);
  const bool xpre = (ws_size >= off + XS_E * 2);

  if (xpre) {
    const long total = 8388608L + 278528 + 16384 + 2048 + FLAG_INTS;
    prep_kernel<true><<<(int)((total + 255) / 256), 256, 0, stream>>>(
        x, init_h, W_ih, b_ih, W_hh, b_hh, xs, wf, hs2, bias, flags);
    recur_kernel<true><<<256, 512, 0, stream>>>(x, b_lin, W_lin, xs, wf, hs2, bias, out, ylogb,
                                                flags);
  } else {
    const long total = 278528L + 16384 + 2048 + FLAG_INTS;
    prep_kernel<false><<<(int)((total + 255) / 256), 256, 0, stream>>>(
        x, init_h, W_ih, b_ih, W_hh, b_hh, xs, wf, hs2, bias, flags);
    recur_kernel<false><<<256, 512, 0, stream>>>(x, b_lin, W_lin, xs, wf, hs2, bias, out, ylogb,
                                                 flags);
  }
}

// Round 6
// 8857.258 us; speedup vs baseline: 2.2113x; 1.0721x over previous
//
#include <hip/hip_runtime.h>
#include <cstdint>
#include <cstddef>

// Autoregressive LSTM cell with softmax feedback. B=256, T=512, D=512, N=64.
// R6 = R5 core (relaxed-atomic LLC message passing, no fences) + latency-hiding
// schedule: split arrive/wait barriers so independent compute runs in each
// barrier's propagation shadow, dot-before-GEMM so ylog publishes early, and
// hi/lo-separated LDS weight arrays (16B-stride b128 reads, bank-conflict-free
// pattern). 256 blocks x 512 thr (8 waves = 4 row-tiles x 2 K-halves), 1/CU.
//
// Per step s:
//   [end of s-1: h-store -> drain -> arrive_A(2s)]
//   x-GEMM (48 MFMA)                  <- overlaps arrive_A propagation
//   wait_A(2s)
//   h-frag atomic loads -> regs; VALU y-dot; merge; ylog store; arrive_B(2s+1)
//   h-GEMM (48 MFMA)                  <- overlaps arrive_B propagation
//   wait_B(2s+1)
//   softmax (regs) + y-feedback MFMA + out[s-1]; pacc K-merge; LSTM; h-store
//   arrive_A(2s+2)

typedef _Float16 f16x8 __attribute__((ext_vector_type(8)));
typedef float f32x4 __attribute__((ext_vector_type(4)));

#define MFMA16(a, b, c_) __builtin_amdgcn_mfma_f32_16x16x32_f16((a), (b), (c_), 0, 0, 0)
#define AGT __HIP_MEMORY_SCOPE_AGENT
#define RLX __ATOMIC_RELAXED

#define FLAG_INTS (256 * 64 + 64)  // 256 padded flag slots + abort word
#define HS2_U32 131072             // per h buffer: 256 rows * 512 u32 (short2/elem)

static __device__ __forceinline__ unsigned short f2b(_Float16 h) {
  return __builtin_bit_cast(unsigned short, h);
}
static __device__ __forceinline__ _Float16 b2f(unsigned short s) {
  return __builtin_bit_cast(_Float16, s);
}

__device__ __forceinline__ void cvt8(const float4 a, const float4 b, f16x8& hi, f16x8& lo) {
  float v[8] = {a.x, a.y, a.z, a.w, b.x, b.y, b.z, b.w};
#pragma unroll
  for (int j = 0; j < 8; ++j) {
    _Float16 h = (_Float16)v[j];
    hi[j] = h;
    lo[j] = (_Float16)(v[j] - (float)h);
  }
}

// ---------------------------------------------------------------------------
// prep (identical to R5). Slot map sigma(q,j)=4q+(j&3)+16*(j>>2) on A and B.
// wf: ct=cb*2+cth, col(l15) = (l15>>2)*512 + cb*8 + cth*4 + (l15&3).
// hs2 buffer0 = init_h, packed u32 = fp16_hi | fp16_lo<<16.
// ---------------------------------------------------------------------------
template <bool XPRE>
__global__ void prep_kernel(const float* __restrict__ x, const float* __restrict__ init_h,
                            const float* __restrict__ W_ih, const float* __restrict__ b_ih,
                            const float* __restrict__ W_hh, const float* __restrict__ b_hh,
                            _Float16* __restrict__ xs, _Float16* __restrict__ wf,
                            unsigned int* __restrict__ hs2, float* __restrict__ bias,
                            int* __restrict__ flags) {
  const long NX = XPRE ? 256L * 512 * 16 * 4 : 0;
  const int NWF = 128 * 34 * 64;
  const int NH2 = 256 * 16 * 4;
  long tid = (long)blockIdx.x * 256 + threadIdx.x;

  if (XPRE && tid < NX) {
    int q = tid & 3, ki = (tid >> 2) & 15, t = (tid >> 6) & 511;
    int row = (int)(tid >> 15);
    const float* s = x + (((size_t)row * 512 + t) * 512 + ki * 32 + 4 * q);
    float4 a = *(const float4*)s, b = *(const float4*)(s + 16);
    f16x8 hi, lo;
    cvt8(a, b, hi, lo);
    _Float16* d = xs + ((((size_t)row * 512 + t) * 16 + ki) * 64 + q * 16);
    *(f16x8*)d = hi;
    *(f16x8*)(d + 8) = lo;
    return;
  }
  long u = tid - NX;
  if (u >= 0 && u < NWF) {
    int l = (int)(u & 63);
    int u2 = (int)(u >> 6);
    int ki = u2 % 34, ct = u2 / 34;
    int cb = ct >> 1, cth = ct & 1;
    int l15 = l & 15;
    int col = (l15 >> 2) * 512 + cb * 8 + cth * 4 + (l15 & 3);
    int k = ki * 32 + 4 * (l >> 4);
    float4 a, b;
    if (k < 512) {
      const float* p = W_ih + (size_t)col * 576;
      a = *(const float4*)(p + k);
      b = *(const float4*)(p + k + 16);
    } else if (k < 1024) {
      const float* p = W_hh + (size_t)col * 512;
      a = *(const float4*)(p + k - 512);
      b = *(const float4*)(p + k - 512 + 16);
    } else {
      const float* p = W_ih + (size_t)col * 576 + 512;
      a = *(const float4*)(p + k - 1024);
      b = *(const float4*)(p + k - 1024 + 16);
    }
    f16x8 hi, lo;
    cvt8(a, b, hi, lo);
    _Float16* d = wf + (((size_t)ct * 34 + ki) * 64 + l) * 16;
    *(f16x8*)d = hi;
    *(f16x8*)(d + 8) = lo;
    return;
  }
  u -= NWF;
  if (u >= 0 && u < NH2) {
    int q = (int)(u & 3), ki = (int)((u >> 2) & 15), row = (int)(u >> 6);
    const float* s = init_h + ((size_t)row * 512 + ki * 32 + 4 * q);
    float4 a = *(const float4*)s, b = *(const float4*)(s + 16);
    float v[8] = {a.x, a.y, a.z, a.w, b.x, b.y, b.z, b.w};
    unsigned int pk[8];
#pragma unroll
    for (int j = 0; j < 8; ++j) {
      _Float16 hh = (_Float16)v[j];
      _Float16 hl = (_Float16)(v[j] - (float)hh);
      pk[j] = (unsigned int)f2b(hh) | ((unsigned int)f2b(hl) << 16);
    }
    unsigned int* base = hs2 + ((size_t)row * 16 + ki) * 32;
    *(uint4*)(base + 4 * q) = make_uint4(pk[0], pk[1], pk[2], pk[3]);
    *(uint4*)(base + 16 + 4 * q) = make_uint4(pk[4], pk[5], pk[6], pk[7]);
    return;
  }
  u -= NH2;
  if (u >= 0 && u < 2048) {
    bias[u] = b_ih[u] + b_hh[u];
    return;
  }
  u -= 2048;
  if (u >= 0 && u < FLAG_INTS) flags[u] = 0;
}

// one k-chunk, both cth col-tiles: 6 MFMAs (3-pass hi/lo). hi/lo arrays separated
// -> 16B-stride lane addressing (conflict-light b128 pattern).
#define GKSTEP(AH, AL, KI)                                                       \
  {                                                                              \
    const f16x8 b0h = *(const f16x8*)(wfl_hi + ((size_t)(KI)*64 + l) * 8);       \
    const f16x8 b1h = *(const f16x8*)(wfl_hi + 17408 + ((size_t)(KI)*64 + l) * 8); \
    const f16x8 b0l = *(const f16x8*)(wfl_lo + ((size_t)(KI)*64 + l) * 8);       \
    const f16x8 b1l = *(const f16x8*)(wfl_lo + 17408 + ((size_t)(KI)*64 + l) * 8); \
    aC0 = MFMA16((AH), b0h, aC0);                                                \
    aC1 = MFMA16((AH), b1h, aC1);                                                \
    aC0 = MFMA16((AL), b0h, aC0);                                                \
    aC1 = MFMA16((AL), b1h, aC1);                                                \
    aC0 = MFMA16((AH), b0l, aC0);                                                \
    aC1 = MFMA16((AH), b1l, aC1);                                                \
  }

template <bool XPRE>
__global__ void __launch_bounds__(512, 2) recur_kernel(
    const float* __restrict__ x, const float* __restrict__ b_lin,
    const float* __restrict__ W_lin, const _Float16* __restrict__ xs,
    const _Float16* __restrict__ wf, unsigned int* __restrict__ hs2,
    const float* __restrict__ bias, float* __restrict__ out, float* __restrict__ ylog,
    int* __restrict__ flags) {
  const int bid = blockIdx.x;
  const int x8 = bid & 7;
  const int g = x8 >> 1;
  const int cb = (x8 & 1) * 32 + (bid >> 3);
  const int tid = threadIdx.x;
  const int l = tid & 63, w = tid >> 6;
  const int l15 = l & 15, q = l >> 4;
  const int kh = w & 1, rtp = w >> 1;

  __shared__ _Float16 wfl_hi[2 * 34 * 64 * 8];  // 68 KiB: B-frag hi
  __shared__ _Float16 wfl_lo[2 * 34 * 64 * 8];  // 68 KiB: B-frag lo
  __shared__ float pacc[4][2][4][64];           // K-half merge (8 KiB)
  __shared__ float lp[4][16];
  __shared__ int s_ab;

  {  // one-time LDS staging (hi/lo split)
    const _Float16* srcw = wf + (size_t)cb * 4352 * 16;
#pragma unroll
    for (int i = 0; i < 9; ++i) {
      int u = tid + i * 512;
      if (u < 4352) {
        const float4* s16 = (const float4*)(srcw + (size_t)u * 16);
        *(float4*)(wfl_hi + (size_t)u * 8) = s16[0];
        *(float4*)(wfl_lo + (size_t)u * 8) = s16[1];
      }
    }
    if (tid == 0) s_ab = 0;
  }
  __syncthreads();

  const int dd = l15 & 3, rr = l15 >> 2;
  float bg[2][4];
#pragma unroll
  for (int c2 = 0; c2 < 2; ++c2)
#pragma unroll
    for (int gi = 0; gi < 4; ++gi) bg[c2][gi] = bias[gi * 512 + cb * 8 + c2 * 4 + dd];
  const float blin = b_lin[cb];

  const int Rw = g * 64 + rtp * 16;
  const int rowA = Rw + l15;
  const int hoff = rowA * 512 + 4 * q;
  const _Float16* xsA = xs + (size_t)rowA * 524288 + q * 16;
  const float* xfA = x + (size_t)rowA * 262144 + 4 * q;
  const float* wl = W_lin + (size_t)cb * 512;

  const int rowE = Rw + 4 * q + rr;
  unsigned int hwo[2];
#pragma unroll
  for (int c2 = 0; c2 < 2; ++c2) {
    int dglob = cb * 8 + c2 * 4 + dd;
    int kiH = dglob >> 5, k32 = dglob & 31;
    int e = 4 * ((k32 & 15) >> 2) + (k32 & 3) + 16 * (k32 >> 4);
    hwo[c2] = (unsigned int)((rowE * 16 + kiH) * 32 + e);
  }

  int* abortf = flags + 256 * 64;

  // Split barrier: ARRIVE publishes (after a drain-sync); WAIT polls all 64 peers.
  auto ARRIVE = [&](int v) {
    __syncthreads();  // drains this block's LLC atomic stores before the flag
    if (tid == 0) __hip_atomic_store(flags + (size_t)(g * 64 + cb) * 64, v, RLX, AGT);
  };
  auto WAIT = [&](int v) -> bool {
    if (tid < 64) {
      int a = 0;
      int* f = flags + ((size_t)g * 64 + tid) * 64;
      int it = 0;
      while (__hip_atomic_load(f, RLX, AGT) < v) {
        __builtin_amdgcn_s_sleep(1);
        if (++it > 400000) {
          a = 1;
          break;
        }
        if ((it & 255) == 0 && __hip_atomic_load(abortf, RLX, AGT) != 0) {
          a = 1;
          break;
        }
      }
      a = __any(a) ? 1 : 0;
      if (tid == 0) {
        if (a) __hip_atomic_store(abortf, 1, RLX, AGT);
        s_ab = a;
      }
    }
    __syncthreads();
    return s_ab != 0;
  };

  float cst[2] = {0.f, 0.f};
  f32x4 aC0, aC1;

#pragma unroll 1
  for (int s = 0; s < 512; ++s) {
    aC0 = (f32x4){0.f, 0.f, 0.f, 0.f};
    aC1 = (f32x4){0.f, 0.f, 0.f, 0.f};

    // ---- x-GEMM: runs in arrive_A's propagation shadow ----
    if (XPRE) {
      const _Float16* xA = xsA + (size_t)s * 1024;
#pragma unroll
      for (int i = 0; i < 8; ++i) {
        int kx = kh * 8 + i;
        f16x8 ah = *(const f16x8*)(xA + kx * 64);
        f16x8 al = *(const f16x8*)(xA + kx * 64 + 8);
        GKSTEP(ah, al, kx);
      }
    } else {
      const float* xp = xfA + (size_t)s * 512;
#pragma unroll 2
      for (int i = 0; i < 8; ++i) {
        int kx = kh * 8 + i;
        float4 av = *(const float4*)(xp + kx * 32);
        float4 bv = *(const float4*)(xp + kx * 32 + 16);
        f16x8 ah, al;
        cvt8(av, bv, ah, al);
        GKSTEP(ah, al, kx);
      }
    }

    // ---- wait_A: h_{s-1} published by all peers ----
    if (s > 0) {
      if (WAIT(2 * s)) return;
    }

    // ---- h-frag loads -> registers (static-indexed) ----
    const unsigned int* hp0 = hs2 + (size_t)(s & 1) * HS2_U32 + hoff;
    f16x8 hh[8], hl[8];
#pragma unroll
    for (int i = 0; i < 8; ++i) {
      const unsigned int* hp = hp0 + (kh * 8 + i) * 32;
      unsigned long long u0 = __hip_atomic_load((const unsigned long long*)hp, RLX, AGT);
      unsigned long long u1 = __hip_atomic_load((const unsigned long long*)(hp + 2), RLX, AGT);
      unsigned long long u2 = __hip_atomic_load((const unsigned long long*)(hp + 16), RLX, AGT);
      unsigned long long u3 = __hip_atomic_load((const unsigned long long*)(hp + 18), RLX, AGT);
      unsigned int wd[8] = {(unsigned int)u0, (unsigned int)(u0 >> 32),
                            (unsigned int)u1, (unsigned int)(u1 >> 32),
                            (unsigned int)u2, (unsigned int)(u2 >> 32),
                            (unsigned int)u3, (unsigned int)(u3 >> 32)};
#pragma unroll
      for (int j = 0; j < 8; ++j) {
        hh[i][j] = b2f((unsigned short)(wd[j] & 0xffffu));
        hl[i][j] = b2f((unsigned short)(wd[j] >> 16));
      }
    }

    // ---- y-logit dot FIRST (VALU), publish ylog early ----
    float dlg = 0.f;
#pragma unroll
    for (int i = 0; i < 8; ++i) {
      int kk = kh * 8 + i;
      float4 wa = *(const float4*)(wl + kk * 32 + 4 * q);
      float4 wb2 = *(const float4*)(wl + kk * 32 + 16 + 4 * q);
      dlg += ((float)hh[i][0] + (float)hl[i][0]) * wa.x +
             ((float)hh[i][1] + (float)hl[i][1]) * wa.y +
             ((float)hh[i][2] + (float)hl[i][2]) * wa.z +
             ((float)hh[i][3] + (float)hl[i][3]) * wa.w +
             ((float)hh[i][4] + (float)hl[i][4]) * wb2.x +
             ((float)hh[i][5] + (float)hl[i][5]) * wb2.y +
             ((float)hh[i][6] + (float)hl[i][6]) * wb2.z +
             ((float)hh[i][7] + (float)hl[i][7]) * wb2.w;
    }
    dlg += __shfl_xor(dlg, 16);
    dlg += __shfl_xor(dlg, 32);
    if (kh == 1 && l < 16) lp[rtp][l15] = dlg;
    __syncthreads();
    if (kh == 0 && l < 16) {
      float full = dlg + lp[rtp][l15] + blin;
      __hip_atomic_store(ylog + ((size_t)g * 64 + cb) * 64 + rtp * 16 + l15, full, RLX, AGT);
    }
    ARRIVE(2 * s + 1);  // arrive_B (syncthreads inside drains the ylog stores)

    // ---- h-GEMM: runs in arrive_B's propagation shadow ----
#pragma unroll
    for (int i = 0; i < 8; ++i) GKSTEP(hh[i], hl[i], 16 + kh * 8 + i);

    // ---- wait_B: ylog complete ----
    if (WAIT(2 * s + 1)) return;

    // ---- y softmax + y-feedback MFMA + out[s-1] ----
    if (s > 0) {
      float la[4][4];
#pragma unroll
      for (int b2 = 0; b2 < 4; ++b2)
#pragma unroll
        for (int m = 0; m < 4; ++m)
          la[b2][m] = __hip_atomic_load(
              ylog + ((size_t)g * 64 + 16 * b2 + 4 * q + m) * 64 + rtp * 16 + l15, RLX, AGT);
      float mx = la[0][0];
#pragma unroll
      for (int b2 = 0; b2 < 4; ++b2)
#pragma unroll
        for (int m = 0; m < 4; ++m) mx = fmaxf(mx, la[b2][m]);
      mx = fmaxf(mx, __shfl_xor(mx, 16));
      mx = fmaxf(mx, __shfl_xor(mx, 32));
      float sm = 0.f;
#pragma unroll
      for (int b2 = 0; b2 < 4; ++b2)
#pragma unroll
        for (int m = 0; m < 4; ++m) {
          la[b2][m] = __expf(la[b2][m] - mx);
          sm += la[b2][m];
        }
      sm += __shfl_xor(sm, 16);
      sm += __shfl_xor(sm, 32);
      float inv = 1.f / sm;
      if (cb == 0 && kh == 0) {
        size_t ob = (((size_t)(g * 64 + rtp * 16 + l15)) * 512 + (s - 1)) * 64;
#pragma unroll
        for (int b2 = 0; b2 < 4; ++b2)
#pragma unroll
          for (int m = 0; m < 4; ++m) out[ob + 16 * b2 + 4 * q + m] = la[b2][m] * inv;
      }
      f16x8 yh;
      if (kh == 0) {
#pragma unroll
        for (int j = 0; j < 8; ++j) yh[j] = (_Float16)(la[j >> 2][j & 3] * inv);
      } else {
#pragma unroll
        for (int j = 0; j < 8; ++j) yh[j] = (_Float16)(la[(j >> 2) + 2][j & 3] * inv);
      }
      const int KY = 32 + kh;
      const f16x8 b0h = *(const f16x8*)(wfl_hi + ((size_t)KY * 64 + l) * 8);
      const f16x8 b1h = *(const f16x8*)(wfl_hi + 17408 + ((size_t)KY * 64 + l) * 8);
      const f16x8 b0l = *(const f16x8*)(wfl_lo + ((size_t)KY * 64 + l) * 8);
      const f16x8 b1l = *(const f16x8*)(wfl_lo + 17408 + ((size_t)KY * 64 + l) * 8);
      aC0 = MFMA16(yh, b0h, aC0);
      aC1 = MFMA16(yh, b1h, aC1);
      aC0 = MFMA16(yh, b0l, aC0);
      aC1 = MFMA16(yh, b1l, aC1);
    }

    // ---- K-half merge ----
    if (kh == 1) {
#pragma unroll
      for (int r = 0; r < 4; ++r) {
        pacc[rtp][0][r][l] = aC0[r];
        pacc[rtp][1][r][l] = aC1[r];
      }
    }
    __syncthreads();
    if (kh == 0) {
#pragma unroll
      for (int r = 0; r < 4; ++r) {
        aC0[r] += pacc[rtp][0][r][l];
        aC1[r] += pacc[rtp][1][r][l];
      }
      // ---- elementwise LSTM + packed h atomic store ----
      const unsigned int wb_ = (unsigned int)(((s & 1) ^ 1) * HS2_U32);
#pragma unroll
      for (int c2 = 0; c2 < 2; ++c2) {
        f32x4 A = c2 ? aC1 : aC0;
        float z[4];
#pragma unroll
        for (int gi = 0; gi < 4; ++gi) {
          int src = (l & 48) | (gi * 4 + dd);
          float v0 = __shfl(A[0], src), v1 = __shfl(A[1], src);
          float v2 = __shfl(A[2], src), v3 = __shfl(A[3], src);
          z[gi] = (rr == 0) ? v0 : (rr == 1) ? v1 : (rr == 2) ? v2 : v3;
        }
        float zi = z[0] + bg[c2][0], zf = z[1] + bg[c2][1];
        float zg = z[2] + bg[c2][2], zo = z[3] + bg[c2][3];
        float iv = 1.f / (1.f + __expf(-zi));
        float fv = 1.f / (1.f + __expf(-zf));
        float eg = __expf(2.f * zg);
        float gv = 1.f - 2.f / (eg + 1.f);
        float ov = 1.f / (1.f + __expf(-zo));
        float cn = fv * cst[c2] + iv * gv;
        cst[c2] = cn;
        float ec = __expf(2.f * cn);
        float th = 1.f - 2.f / (ec + 1.f);
        float hv = ov * th;
        _Float16 hh2 = (_Float16)hv;
        _Float16 hl2 = (_Float16)(hv - (float)hh2);
        unsigned int pk = (unsigned int)f2b(hh2) | ((unsigned int)f2b(hl2) << 16);
        __hip_atomic_store(hs2 + wb_ + hwo[c2], pk, RLX, AGT);
      }
    }
    ARRIVE(2 * s + 2);  // arrive_A for step s+1 (sync drains the h stores)
  }

  // ---- epilogue: y_511 from h_511 (buffer 0) ----
  if (WAIT(1024)) return;
  {
    const unsigned int* hp0 = hs2 + hoff;
    float dlg = 0.f;
#pragma unroll
    for (int i = 0; i < 8; ++i) {
      int kk = kh * 8 + i;
      const unsigned int* hp = hp0 + kk * 32;
      unsigned long long u0 = __hip_atomic_load((const unsigned long long*)hp, RLX, AGT);
      unsigned long long u1 = __hip_atomic_load((const unsigned long long*)(hp + 2), RLX, AGT);
      unsigned long long u2 = __hip_atomic_load((const unsigned long long*)(hp + 16), RLX, AGT);
      unsigned long long u3 = __hip_atomic_load((const unsigned long long*)(hp + 18), RLX, AGT);
      unsigned int wd[8] = {(unsigned int)u0, (unsigned int)(u0 >> 32),
                            (unsigned int)u1, (unsigned int)(u1 >> 32),
                            (unsigned int)u2, (unsigned int)(u2 >> 32),
                            (unsigned int)u3, (unsigned int)(u3 >> 32)};
      float4 wa = *(const float4*)(wl + kk * 32 + 4 * q);
      float4 wb2 = *(const float4*)(wl + kk * 32 + 16 + 4 * q);
      float hv0[8];
#pragma unroll
      for (int j = 0; j < 8; ++j)
        hv0[j] = (float)b2f((unsigned short)(wd[j] & 0xffffu)) +
                 (float)b2f((unsigned short)(wd[j] >> 16));
      dlg += hv0[0] * wa.x + hv0[1] * wa.y + hv0[2] * wa.z + hv0[3] * wa.w + hv0[4] * wb2.x +
             hv0[5] * wb2.y + hv0[6] * wb2.z + hv0[7] * wb2.w;
    }
    dlg += __shfl_xor(dlg, 16);
    dlg += __shfl_xor(dlg, 32);
    if (kh == 1 && l < 16) lp[rtp][l15] = dlg;
    __syncthreads();
    if (kh == 0 && l < 16)
      __hip_atomic_store(ylog + ((size_t)g * 64 + cb) * 64 + rtp * 16 + l15,
                         dlg + lp[rtp][l15] + blin, RLX, AGT);
  }
  ARRIVE(1025);
  if (WAIT(1025)) return;
  if (cb == 0 && kh == 0) {
    float la[4][4];
#pragma unroll
    for (int b2 = 0; b2 < 4; ++b2)
#pragma unroll
      for (int m = 0; m < 4; ++m)
        la[b2][m] = __hip_atomic_load(
            ylog + ((size_t)g * 64 + 16 * b2 + 4 * q + m) * 64 + rtp * 16 + l15, RLX, AGT);
    float mx = la[0][0];
#pragma unroll
    for (int b2 = 0; b2 < 4; ++b2)
#pragma unroll
      for (int m = 0; m < 4; ++m) mx = fmaxf(mx, la[b2][m]);
    mx = fmaxf(mx, __shfl_xor(mx, 16));
    mx = fmaxf(mx, __shfl_xor(mx, 32));
    float sm = 0.f;
#pragma unroll
    for (int b2 = 0; b2 < 4; ++b2)
#pragma unroll
      for (int m = 0; m < 4; ++m) {
        la[b2][m] = __expf(la[b2][m] - mx);
        sm += la[b2][m];
      }
    sm += __shfl_xor(sm, 16);
    sm += __shfl_xor(sm, 32);
    float inv = 1.f / sm;
    size_t ob = (((size_t)(g * 64 + rtp * 16 + l15)) * 512 + 511) * 64;
#pragma unroll
    for (int b2 = 0; b2 < 4; ++b2)
#pragma unroll
      for (int m = 0; m < 4; ++m) out[ob + 16 * b2 + 4 * q + m] = la[b2][m] * inv;
  }
}

extern "C" void kernel_launch(void* const* d_in, const int* in_sizes, int n_in, void* d_out,
                              int out_size, void* d_ws, size_t ws_size, hipStream_t stream) {
  const float* x = (const float*)d_in[0];
  const float* init_h = (const float*)d_in[1];
  const float* W_ih = (const float*)d_in[2];
  const float* b_ih = (const float*)d_in[3];
  const float* W_hh = (const float*)d_in[4];
  const float* b_hh = (const float*)d_in[5];
  const float* W_lin = (const float*)d_in[6];
  const float* b_lin = (const float*)d_in[7];
  float* out = (float*)d_out;
  (void)in_sizes;
  (void)n_in;
  (void)out_size;

  char* ws = (char*)d_ws;
  size_t off = 0;
  auto take = [&](size_t bytes) -> char* {
    char* r = ws + off;
    off = (off + bytes + 255) & ~(size_t)255;
    return r;
  };
  const size_t WF_E = (size_t)128 * 34 * 64 * 16;
  const size_t XS_E = (size_t)256 * 512 * 16 * 64;

  _Float16* wf = (_Float16*)take(WF_E * 2);
  unsigned int* hs2 = (unsigned int*)take((size_t)2 * HS2_U32 * 4);
  float* bias = (float*)take(2048 * 4);
  float* ylogb = (float*)take((size_t)4 * 64 * 64 * 4);
  int* flags = (int*)take((size_t)FLAG_INTS * 4);
  if (ws_size < off) return;
  _Float16* xs = (_Float16*)(ws + off);
  const bool xpre = (ws_size >= off + XS_E * 2);

  if (xpre) {
    const long total = 8388608L + 278528 + 16384 + 2048 + FLAG_INTS;
    prep_kernel<true><<<(int)((total + 255) / 256), 256, 0, stream>>>(
        x, init_h, W_ih, b_ih, W_hh, b_hh, xs, wf, hs2, bias, flags);
    recur_kernel<true><<<256, 512, 0, stream>>>(x, b_lin, W_lin, xs, wf, hs2, bias, out, ylogb,
                                                flags);
  } else {
    const long total = 278528L + 16384 + 2048 + FLAG_INTS;
    prep_kernel<false><<<(int)((total + 255) / 256), 256, 0, stream>>>(
        x, init_h, W_ih, b_ih, W_hh, b_hh, xs, wf, hs2, bias, flags);
    recur_kernel<false><<<256, 512, 0, stream>>>(x, b_lin, W_lin, xs, wf, hs2, bias, out, ylogb,
                                                 flags);
  }
}